// Round 1
// baseline (1162.769 us; speedup 1.0000x reference)
//
#include <hip/hip_runtime.h>
#include <cstdint>
#include <cstddef>

#define B_  2
#define S_  2048
#define D_  4096
#define NH  32
#define NKV 8
#define HD  128

typedef unsigned short u16;
typedef unsigned int   u32;
typedef __attribute__((ext_vector_type(8))) short short8;
typedef __attribute__((ext_vector_type(4))) float f32x4;

__device__ __forceinline__ u16 f2bf(float f) {
  u32 u = __float_as_uint(f);
  u32 r = (u + 0x7FFFu + ((u >> 16) & 1u)) >> 16;  // RNE
  return (u16)r;
}
__device__ __forceinline__ float bf2f(u32 lo16) {
  return __uint_as_float(lo16 << 16);
}
__device__ __forceinline__ void load_lds16(const void* g, void* lds) {
  __builtin_amdgcn_global_load_lds(
      (const __attribute__((address_space(1))) u32*)g,
      (__attribute__((address_space(3))) u32*)lds, 16, 0, 0);
}

// ---------------- fp32 -> bf16 converter (8 elems/thread) ----------------
__global__ __launch_bounds__(256) void f32_to_bf16_k(const float* __restrict__ src,
                                                     u16* __restrict__ dst, int n8) {
  int i = blockIdx.x * 256 + threadIdx.x;
  if (i >= n8) return;
  const float4* s = (const float4*)src + (size_t)i * 2;
  float4 a = s[0], b = s[1];
  u32 w0 = (u32)f2bf(a.x) | ((u32)f2bf(a.y) << 16);
  u32 w1 = (u32)f2bf(a.z) | ((u32)f2bf(a.w) << 16);
  u32 w2 = (u32)f2bf(b.x) | ((u32)f2bf(b.y) << 16);
  u32 w3 = (u32)f2bf(b.z) | ((u32)f2bf(b.w) << 16);
  uint4 o; o.x = w0; o.y = w1; o.z = w2; o.w = w3;
  *((uint4*)dst + i) = o;
}

// ---------------- RoPE in-place on [BH][S][128] bf16 ----------------
// chunk = 8 elems = 4 interleaved (even,odd) pairs
__global__ __launch_bounds__(256) void rope_k(u16* __restrict__ t,
                                              const float* __restrict__ ct,
                                              const float* __restrict__ st, int nchunks) {
  int i = blockIdx.x * 256 + threadIdx.x;
  if (i >= nchunks) return;
  int j8 = i & 15;            // which 8-elem chunk within the 128-d row
  int s  = (i >> 4) & (S_ - 1);
  uint4 v = *((uint4*)t + i);
  float4 c  = *(const float4*)(ct + (size_t)s * 64 + j8 * 4);
  float4 sn = *(const float4*)(st + (size_t)s * 64 + j8 * 4);
  u32 w[4] = {v.x, v.y, v.z, v.w};
  float cc[4] = {c.x, c.y, c.z, c.w};
  float ss[4] = {sn.x, sn.y, sn.z, sn.w};
#pragma unroll
  for (int j = 0; j < 4; ++j) {
    float e = bf2f(w[j] & 0xffffu), o = bf2f(w[j] >> 16);
    float e2 = e * cc[j] - o * ss[j];
    float o2 = e * ss[j] + o * cc[j];
    w[j] = (u32)f2bf(e2) | ((u32)f2bf(o2) << 16);
  }
  uint4 ov; ov.x = w[0]; ov.y = w[1]; ov.z = w[2]; ov.w = w[3];
  *((uint4*)t + i) = ov;
}

// ---------------- GEMM: C[m,n] = sum_k A[m,k]*Bw[n,k] (both row-major bf16) ---
// MODE 0: fp32 row-major C[M][N]
// MODE 1: bf16 -> [b][h][s][128]    (h = n>>7, d = n&127, b = m>>11, s = m&2047)
// MODE 2: bf16 -> [b][h][d][s]      (V transposed)
template <int MODE>
__global__ __launch_bounds__(256)
void gemm_bt(const u16* __restrict__ A, const u16* __restrict__ Bw,
             void* __restrict__ Cout, int M, int N, int K, int Hh) {
  const int tid = threadIdx.x;
  const int lid = tid & 63, w = tid >> 6;
  const int lr = lid & 15, lg = lid >> 4;
  const int wm = w >> 1, wn = w & 1;
  const int bm = blockIdx.y * 128, bn = blockIdx.x * 128;
  __shared__ __align__(16) u16 Al[128 * 64];
  __shared__ __align__(16) u16 Bl[128 * 64];
  f32x4 acc[4][4];
#pragma unroll
  for (int i = 0; i < 4; ++i)
#pragma unroll
    for (int j = 0; j < 4; ++j) acc[i][j] = (f32x4){0.f, 0.f, 0.f, 0.f};

  const int rowst = tid >> 3;   // + i*32
  const int cbst  = tid & 7;

  for (int k0 = 0; k0 < K; k0 += 64) {
    __syncthreads();
#pragma unroll
    for (int i = 0; i < 4; ++i) {
      int row = i * 32 + rowst;
      load_lds16(A + (size_t)(bm + row) * K + k0 + cbst * 8, &Al[(i * 256 + w * 64) * 8]);
    }
#pragma unroll
    for (int i = 0; i < 4; ++i) {
      int row = i * 32 + rowst;
      load_lds16(Bw + (size_t)(bn + row) * K + k0 + cbst * 8, &Bl[(i * 256 + w * 64) * 8]);
    }
    __syncthreads();
#pragma unroll
    for (int ks = 0; ks < 2; ++ks) {
      short8 af[4], bf[4];
#pragma unroll
      for (int mi = 0; mi < 4; ++mi)
        af[mi] = *(const short8*)&Al[(wm * 64 + mi * 16 + lr) * 64 + ks * 32 + lg * 8];
#pragma unroll
      for (int ni = 0; ni < 4; ++ni)
        bf[ni] = *(const short8*)&Bl[(wn * 64 + ni * 16 + lr) * 64 + ks * 32 + lg * 8];
#pragma unroll
      for (int mi = 0; mi < 4; ++mi)
#pragma unroll
        for (int ni = 0; ni < 4; ++ni)
          acc[mi][ni] = __builtin_amdgcn_mfma_f32_16x16x32_bf16(af[mi], bf[ni], acc[mi][ni], 0, 0, 0);
    }
  }
#pragma unroll
  for (int mi = 0; mi < 4; ++mi)
#pragma unroll
    for (int ni = 0; ni < 4; ++ni)
#pragma unroll
      for (int v = 0; v < 4; ++v) {
        int m = bm + wm * 64 + mi * 16 + lg * 4 + v;
        int n = bn + wn * 64 + ni * 16 + lr;
        float val = acc[mi][ni][v];
        if (MODE == 0) {
          ((float*)Cout)[(size_t)m * N + n] = val;
        } else if (MODE == 1) {
          int b = m >> 11, s = m & (S_ - 1), hh = n >> 7, d = n & (HD - 1);
          ((u16*)Cout)[(((size_t)(b * Hh + hh)) * S_ + s) * HD + d] = f2bf(val);
        } else {
          int b = m >> 11, s = m & (S_ - 1), hh = n >> 7, d = n & (HD - 1);
          ((u16*)Cout)[(((size_t)(b * Hh + hh)) * HD + d) * S_ + s] = f2bf(val);
        }
      }
}

// ---------------- Flash attention: 1 block per (qi, h, b); 4 waves x 32 q-rows
__global__ __launch_bounds__(256)
void attn_k(const u16* __restrict__ Qr, const u16* __restrict__ Kr,
            const u16* __restrict__ Vt, u16* __restrict__ Ao) {
  const int qi = blockIdx.x, h = blockIdx.y, b = blockIdx.z;
  const int kvh = h >> 2;
  const int tid = threadIdx.x, lid = tid & 63, w = tid >> 6;
  const int lr = lid & 15, lg = lid >> 4;
  const int qb = qi * 128;
  __shared__ __align__(16) u16 Kl[64 * 128];   // [kv][d], XOR-swizzled 16B chunks
  __shared__ __align__(16) u16 Vl[128 * 64];   // [d][kv], XOR-swizzled
  __shared__ __align__(16) u16 Pl[4 * 32 * 64];// per-wave [q][kv], XOR-swizzled

  // Q fragments in registers: rows qb + w*32 + mi*16 + lr, k-slices of 32 over d=128
  short8 qf[2][4];
  const size_t qbase = ((size_t)(b * NH + h)) * S_ * HD;
#pragma unroll
  for (int mi = 0; mi < 2; ++mi)
#pragma unroll
    for (int ks = 0; ks < 4; ++ks)
      qf[mi][ks] = *(const short8*)&Qr[qbase + (size_t)(qb + w * 32 + mi * 16 + lr) * HD + ks * 32 + lg * 8];

  float mrow[2][4], ssum[2][4];
  f32x4 oacc[2][8];
#pragma unroll
  for (int mi = 0; mi < 2; ++mi) {
#pragma unroll
    for (int v = 0; v < 4; ++v) { mrow[mi][v] = -INFINITY; ssum[mi][v] = 0.f; }
#pragma unroll
    for (int nd = 0; nd < 8; ++nd) oacc[mi][nd] = (f32x4){0.f, 0.f, 0.f, 0.f};
  }
  const size_t kbase = ((size_t)(b * NKV + kvh)) * S_ * HD;
  const size_t vbase = ((size_t)(b * NKV + kvh)) * HD * S_;
  const int ntiles = qi * 2 + 2;
  const float scale = 0.088388347648318447f;  // 1/sqrt(128)

  for (int t = 0; t < ntiles; ++t) {
    const int kt = t * 64;
    __syncthreads();
    // stage K tile [64][128]: 16 chunks/row; source pre-swizzled (G21)
#pragma unroll
    for (int i = 0; i < 4; ++i) {
      int c = i * 256 + tid;
      int row = c >> 4, cb = c & 15;
      int cbs = (cb & 8) | ((cb ^ row) & 7);
      load_lds16(&Kr[kbase + (size_t)(kt + row) * HD + cbs * 8], &Kl[(i * 256 + w * 64) * 8]);
    }
    // stage V^T tile [128][64]: 8 chunks/row
#pragma unroll
    for (int i = 0; i < 4; ++i) {
      int c = i * 256 + tid;
      int d = c >> 3, cb = c & 7;
      int cbs = (cb ^ d) & 7;
      load_lds16(&Vt[vbase + (size_t)d * S_ + kt + cbs * 8], &Vl[(i * 256 + w * 64) * 8]);
    }
    __syncthreads();

    // ---- scores = Q K^T
    f32x4 sc[2][4];
#pragma unroll
    for (int mi = 0; mi < 2; ++mi)
#pragma unroll
      for (int ni = 0; ni < 4; ++ni) sc[mi][ni] = (f32x4){0.f, 0.f, 0.f, 0.f};
#pragma unroll
    for (int ks = 0; ks < 4; ++ks) {
      short8 kf[4];
#pragma unroll
      for (int ni = 0; ni < 4; ++ni) {
        int row = ni * 16 + lr;
        int ch = ks * 4 + lg;
        int chs = (ch & 8) | ((ch ^ row) & 7);
        kf[ni] = *(const short8*)&Kl[row * 128 + chs * 8];
      }
#pragma unroll
      for (int mi = 0; mi < 2; ++mi)
#pragma unroll
        for (int ni = 0; ni < 4; ++ni)
          sc[mi][ni] = __builtin_amdgcn_mfma_f32_16x16x32_bf16(qf[mi][ks], kf[ni], sc[mi][ni], 0, 0, 0);
    }

    // ---- online softmax (rows live on (lg,reg); cols on lr)
    const bool edge = (kt + 64 > qb);
#pragma unroll
    for (int mi = 0; mi < 2; ++mi) {
#pragma unroll
      for (int v = 0; v < 4; ++v) {
        const int q_abs = qb + w * 32 + mi * 16 + lg * 4 + v;
        float sv[4];
        float rmax = -INFINITY;
#pragma unroll
        for (int ni = 0; ni < 4; ++ni) {
          float s = sc[mi][ni][v] * scale;
          if (edge && (kt + ni * 16 + lr > q_abs)) s = -INFINITY;
          sv[ni] = s;
          rmax = fmaxf(rmax, s);
        }
        rmax = fmaxf(rmax, __shfl_xor(rmax, 1));
        rmax = fmaxf(rmax, __shfl_xor(rmax, 2));
        rmax = fmaxf(rmax, __shfl_xor(rmax, 4));
        rmax = fmaxf(rmax, __shfl_xor(rmax, 8));
        const float mold = mrow[mi][v];
        const float mnew = fmaxf(mold, rmax);
        const float fr = __expf(mold - mnew);  // expf(-inf)=0 on first tile
        float psum = 0.f;
        const int prow = mi * 16 + lg * 4 + v;
#pragma unroll
        for (int ni = 0; ni < 4; ++ni) {
          float p = __expf(sv[ni] - mnew);
          psum += p;
          int col = ni * 16 + lr;
          Pl[w * 2048 + prow * 64 + (((col >> 3) ^ prow) & 7) * 8 + (col & 7)] = f2bf(p);
        }
        psum += __shfl_xor(psum, 1);
        psum += __shfl_xor(psum, 2);
        psum += __shfl_xor(psum, 4);
        psum += __shfl_xor(psum, 8);
        ssum[mi][v] = ssum[mi][v] * fr + psum;
        mrow[mi][v] = mnew;
#pragma unroll
        for (int nd = 0; nd < 8; ++nd) oacc[mi][nd][v] *= fr;
      }
    }
    asm volatile("s_waitcnt lgkmcnt(0)" ::: "memory");  // P writes visible to own wave

    // ---- O += P V
#pragma unroll
    for (int ks = 0; ks < 2; ++ks) {
      short8 pf[2];
#pragma unroll
      for (int mi = 0; mi < 2; ++mi) {
        int row = mi * 16 + lr;
        int ch = ks * 4 + lg;
        pf[mi] = *(const short8*)&Pl[w * 2048 + row * 64 + ((ch ^ row) & 7) * 8];
      }
#pragma unroll
      for (int nd = 0; nd < 8; ++nd) {
        int rowv = nd * 16 + lr;
        int ch = ks * 4 + lg;
        short8 vf = *(const short8*)&Vl[rowv * 64 + ((ch ^ rowv) & 7) * 8];
#pragma unroll
        for (int mi = 0; mi < 2; ++mi)
          oacc[mi][nd] = __builtin_amdgcn_mfma_f32_16x16x32_bf16(pf[mi], vf, oacc[mi][nd], 0, 0, 0);
      }
    }
  }

  // epilogue: O /= sum, write bf16 token-major [b*S+q][h*128+d]
#pragma unroll
  for (int mi = 0; mi < 2; ++mi)
#pragma unroll
    for (int v = 0; v < 4; ++v) {
      const int q_abs = qb + w * 32 + mi * 16 + lg * 4 + v;
      const float inv = 1.f / ssum[mi][v];
#pragma unroll
      for (int nd = 0; nd < 8; ++nd) {
        int d = nd * 16 + lr;
        Ao[((size_t)(b * S_ + q_abs)) * D_ + h * HD + d] = f2bf(oacc[mi][nd][v] * inv);
      }
    }
}

// ---------------- host launch ----------------
extern "C" void kernel_launch(void* const* d_in, const int* in_sizes, int n_in,
                              void* d_out, int out_size, void* d_ws, size_t ws_size,
                              hipStream_t stream) {
  const float* x  = (const float*)d_in[0];
  const float* wq = (const float*)d_in[1];
  const float* wk = (const float*)d_in[2];
  const float* wv = (const float*)d_in[3];
  const float* wo = (const float*)d_in[4];
  const float* fc = (const float*)d_in[5];
  const float* fs = (const float*)d_in[6];
  // d_in[7]=mask (causal, implemented analytically), d_in[8]=start_pos (0)

  const size_t SZ_X  = (size_t)B_ * S_ * D_ * 2;        // 33,554,432
  const size_t SZ_WQ = (size_t)D_ * D_ * 2;             // 33,554,432
  const size_t SZ_WK = (size_t)NKV * HD * D_ * 2;       // 8,388,608
  char* ws = (char*)d_ws;
  u16* Xb  = (u16*)(ws);
  u16* Wqb = (u16*)(ws + SZ_X);
  u16* Wkb = (u16*)(ws + SZ_X + SZ_WQ);
  u16* Wvb = (u16*)(ws + SZ_X + SZ_WQ + SZ_WK);
  u16* Wob = (u16*)(ws + SZ_X + SZ_WQ + 2 * SZ_WK);
  u16* Qr  = (u16*)(ws + SZ_X + 2 * SZ_WQ + 2 * SZ_WK);
  u16* Kr  = (u16*)(ws + 2 * SZ_X + 2 * SZ_WQ + 2 * SZ_WK);
  u16* Vt  = (u16*)(ws + 2 * SZ_X + 2 * SZ_WQ + 3 * SZ_WK);
  u16* Ao  = (u16*)(ws + 2 * SZ_X + 2 * SZ_WQ + 4 * SZ_WK);
  const size_t NEEDED = 3 * SZ_X + 2 * SZ_WQ + 4 * SZ_WK;  // 201,326,592
  if (ws_size < NEEDED) return;

  const int nX = B_ * S_ * D_;       // 16,777,216
  const int nWQ = D_ * D_;
  const int nWK = NKV * HD * D_;     // 4,194,304
  f32_to_bf16_k<<<nX / 8 / 256, 256, 0, stream>>>(x, Xb, nX / 8);
  f32_to_bf16_k<<<nWQ / 8 / 256, 256, 0, stream>>>(wq, Wqb, nWQ / 8);
  f32_to_bf16_k<<<nWK / 8 / 256, 256, 0, stream>>>(wk, Wkb, nWK / 8);
  f32_to_bf16_k<<<nWK / 8 / 256, 256, 0, stream>>>(wv, Wvb, nWK / 8);
  f32_to_bf16_k<<<nWQ / 8 / 256, 256, 0, stream>>>(wo, Wob, nWQ / 8);

  gemm_bt<1><<<dim3(D_ / 128, (B_ * S_) / 128), 256, 0, stream>>>(Xb, Wqb, Qr, B_ * S_, D_, D_, NH);
  gemm_bt<1><<<dim3((NKV * HD) / 128, (B_ * S_) / 128), 256, 0, stream>>>(Xb, Wkb, Kr, B_ * S_, NKV * HD, D_, NKV);
  gemm_bt<2><<<dim3((NKV * HD) / 128, (B_ * S_) / 128), 256, 0, stream>>>(Xb, Wvb, Vt, B_ * S_, NKV * HD, D_, NKV);

  const int qChunks = B_ * NH * S_ * (HD / 8);   // 2,097,152
  const int kChunks = B_ * NKV * S_ * (HD / 8);  // 524,288
  rope_k<<<qChunks / 256, 256, 0, stream>>>(Qr, fc, fs, qChunks);
  rope_k<<<kChunks / 256, 256, 0, stream>>>(Kr, fc, fs, kChunks);

  attn_k<<<dim3(S_ / 128, NH, B_), 256, 0, stream>>>(Qr, Kr, Vt, Ao);

  gemm_bt<0><<<dim3(D_ / 128, (B_ * S_) / 128), 256, 0, stream>>>(Ao, Wob, d_out, B_ * S_, D_, D_, 0);
}

// Round 2
// 905.779 us; speedup vs baseline: 1.2837x; 1.2837x over previous
//
#include <hip/hip_runtime.h>
#include <cstdint>
#include <cstddef>

#define B_  2
#define S_  2048
#define D_  4096
#define NH  32
#define NKV 8
#define HD  128

typedef unsigned short u16;
typedef unsigned int   u32;
typedef __attribute__((ext_vector_type(8))) short short8;
typedef __attribute__((ext_vector_type(4))) float f32x4;

__device__ __forceinline__ u16 f2bf(float f) {
  u32 u = __float_as_uint(f);
  u32 r = (u + 0x7FFFu + ((u >> 16) & 1u)) >> 16;  // RNE
  return (u16)r;
}
__device__ __forceinline__ float bf2f(u32 lo16) {
  return __uint_as_float(lo16 << 16);
}
__device__ __forceinline__ void load_lds16(const void* g, void* lds) {
  __builtin_amdgcn_global_load_lds(
      (const __attribute__((address_space(1))) u32*)g,
      (__attribute__((address_space(3))) u32*)lds, 16, 0, 0);
}

// ---------------- fp32 -> bf16 converter (8 elems/thread) ----------------
__global__ __launch_bounds__(256) void f32_to_bf16_k(const float* __restrict__ src,
                                                     u16* __restrict__ dst, int n8) {
  int i = blockIdx.x * 256 + threadIdx.x;
  if (i >= n8) return;
  const float4* s = (const float4*)src + (size_t)i * 2;
  float4 a = s[0], b = s[1];
  u32 w0 = (u32)f2bf(a.x) | ((u32)f2bf(a.y) << 16);
  u32 w1 = (u32)f2bf(a.z) | ((u32)f2bf(a.w) << 16);
  u32 w2 = (u32)f2bf(b.x) | ((u32)f2bf(b.y) << 16);
  u32 w3 = (u32)f2bf(b.z) | ((u32)f2bf(b.w) << 16);
  uint4 o; o.x = w0; o.y = w1; o.z = w2; o.w = w3;
  *((uint4*)dst + i) = o;
}

// ---------------- RoPE in-place on [BH][S][128] bf16 ----------------
__global__ __launch_bounds__(256) void rope_k(u16* __restrict__ t,
                                              const float* __restrict__ ct,
                                              const float* __restrict__ st, int nchunks) {
  int i = blockIdx.x * 256 + threadIdx.x;
  if (i >= nchunks) return;
  int j8 = i & 15;            // which 8-elem chunk within the 128-d row
  int s  = (i >> 4) & (S_ - 1);
  uint4 v = *((uint4*)t + i);
  float4 c  = *(const float4*)(ct + (size_t)s * 64 + j8 * 4);
  float4 sn = *(const float4*)(st + (size_t)s * 64 + j8 * 4);
  u32 w[4] = {v.x, v.y, v.z, v.w};
  float cc[4] = {c.x, c.y, c.z, c.w};
  float ss[4] = {sn.x, sn.y, sn.z, sn.w};
#pragma unroll
  for (int j = 0; j < 4; ++j) {
    float e = bf2f(w[j] & 0xffffu), o = bf2f(w[j] >> 16);
    float e2 = e * cc[j] - o * ss[j];
    float o2 = e * ss[j] + o * cc[j];
    w[j] = (u32)f2bf(e2) | ((u32)f2bf(o2) << 16);
  }
  uint4 ov; ov.x = w[0]; ov.y = w[1]; ov.z = w[2]; ov.w = w[3];
  *((uint4*)t + i) = ov;
}

// ---------------- GEMM: C[m,n] = sum_k A[m,k]*Bw[n,k] (both row-major bf16) ---
template <int MODE>
__global__ __launch_bounds__(256)
void gemm_bt(const u16* __restrict__ A, const u16* __restrict__ Bw,
             void* __restrict__ Cout, int M, int N, int K, int Hh) {
  const int tid = threadIdx.x;
  const int lid = tid & 63, w = tid >> 6;
  const int lr = lid & 15, lg = lid >> 4;
  const int wm = w >> 1, wn = w & 1;
  const int bm = blockIdx.y * 128, bn = blockIdx.x * 128;
  __shared__ __align__(16) u16 Al[128 * 64];
  __shared__ __align__(16) u16 Bl[128 * 64];
  f32x4 acc[4][4];
#pragma unroll
  for (int i = 0; i < 4; ++i)
#pragma unroll
    for (int j = 0; j < 4; ++j) acc[i][j] = (f32x4){0.f, 0.f, 0.f, 0.f};

  const int rowst = tid >> 3;   // + i*32
  const int cbst  = tid & 7;

  for (int k0 = 0; k0 < K; k0 += 64) {
    __syncthreads();
#pragma unroll
    for (int i = 0; i < 4; ++i) {
      int row = i * 32 + rowst;
      load_lds16(A + (size_t)(bm + row) * K + k0 + cbst * 8, &Al[(i * 256 + w * 64) * 8]);
    }
#pragma unroll
    for (int i = 0; i < 4; ++i) {
      int row = i * 32 + rowst;
      load_lds16(Bw + (size_t)(bn + row) * K + k0 + cbst * 8, &Bl[(i * 256 + w * 64) * 8]);
    }
    __syncthreads();
#pragma unroll
    for (int ks = 0; ks < 2; ++ks) {
      short8 af[4], bf[4];
#pragma unroll
      for (int mi = 0; mi < 4; ++mi)
        af[mi] = *(const short8*)&Al[(wm * 64 + mi * 16 + lr) * 64 + ks * 32 + lg * 8];
#pragma unroll
      for (int ni = 0; ni < 4; ++ni)
        bf[ni] = *(const short8*)&Bl[(wn * 64 + ni * 16 + lr) * 64 + ks * 32 + lg * 8];
#pragma unroll
      for (int mi = 0; mi < 4; ++mi)
#pragma unroll
        for (int ni = 0; ni < 4; ++ni)
          acc[mi][ni] = __builtin_amdgcn_mfma_f32_16x16x32_bf16(af[mi], bf[ni], acc[mi][ni], 0, 0, 0);
    }
  }
#pragma unroll
  for (int mi = 0; mi < 4; ++mi)
#pragma unroll
    for (int ni = 0; ni < 4; ++ni)
#pragma unroll
      for (int v = 0; v < 4; ++v) {
        int m = bm + wm * 64 + mi * 16 + lg * 4 + v;
        int n = bn + wn * 64 + ni * 16 + lr;
        float val = acc[mi][ni][v];
        if (MODE == 0) {
          ((float*)Cout)[(size_t)m * N + n] = val;
        } else if (MODE == 1) {
          int b = m >> 11, s = m & (S_ - 1), hh = n >> 7, d = n & (HD - 1);
          ((u16*)Cout)[(((size_t)(b * Hh + hh)) * S_ + s) * HD + d] = f2bf(val);
        } else {
          int b = m >> 11, s = m & (S_ - 1), hh = n >> 7, d = n & (HD - 1);
          ((u16*)Cout)[(((size_t)(b * Hh + hh)) * HD + d) * S_ + s] = f2bf(val);
        }
      }
}

// ---------------- Flash attention ----------------
// Grid (8, NH, B): block x handles q-tiles (15-x) then (x) -> 34 tile-steps each
// 4 waves x 32 q-rows; K/V double-buffered in LDS; exp2-domain online softmax;
// row-sum via MFMA against all-ones B; defer-max rescale (THR=8 log2 units).
__global__ __launch_bounds__(256)
void attn_k(const u16* __restrict__ Qr, const u16* __restrict__ Kr,
            const u16* __restrict__ Vt, u16* __restrict__ Ao) {
  const int xp = blockIdx.x, h = blockIdx.y, b = blockIdx.z;
  const int kvh = h >> 2;
  const int tid = threadIdx.x, lid = tid & 63, w = tid >> 6;
  const int lr = lid & 15, lg = lid >> 4;
  __shared__ __align__(16) u16 Kl[2][64 * 128];   // [kv][d], XOR-swizzled 16B chunks
  __shared__ __align__(16) u16 Vl[2][128 * 64];   // [d][kv], XOR-swizzled
  __shared__ __align__(16) u16 Pl[4 * 32 * 64];   // per-wave [q][kv], XOR-swizzled

  const size_t qbase = ((size_t)(b * NH + h)) * S_ * HD;
  const size_t kbase = ((size_t)(b * NKV + kvh)) * S_ * HD;
  const size_t vbase = ((size_t)(b * NKV + kvh)) * HD * S_;
  const float scl = 0.08838834764831845f * 1.44269504088896340f;  // log2e/sqrt(128)

  short8 onesv;
#pragma unroll
  for (int j = 0; j < 8; ++j) onesv[j] = (short)0x3F80;  // bf16 1.0

#define STAGE(BUF, KT)                                                              \
  do {                                                                              \
    _Pragma("unroll")                                                               \
    for (int i_ = 0; i_ < 4; ++i_) {                                                \
      int c_ = i_ * 256 + tid;                                                      \
      int row_ = c_ >> 4, cb_ = c_ & 15;                                            \
      int cbs_ = (cb_ & 8) | ((cb_ ^ row_) & 7);                                    \
      load_lds16(&Kr[kbase + (size_t)((KT) + row_) * HD + cbs_ * 8],                \
                 &Kl[BUF][(i_ * 256 + w * 64) * 8]);                                \
    }                                                                               \
    _Pragma("unroll")                                                               \
    for (int i_ = 0; i_ < 4; ++i_) {                                                \
      int c_ = i_ * 256 + tid;                                                      \
      int d_ = c_ >> 3, cb_ = c_ & 7;                                               \
      int cbs_ = (cb_ ^ d_) & 7;                                                    \
      load_lds16(&Vt[vbase + (size_t)d_ * S_ + (KT) + cbs_ * 8],                    \
                 &Vl[BUF][(i_ * 256 + w * 64) * 8]);                                \
    }                                                                               \
  } while (0)

  for (int part = 0; part < 2; ++part) {
    const int qi = part ? xp : (15 - xp);
    const int qb = qi * 128;
    const int ntiles = qi * 2 + 2;

    // Q fragments for this q-tile
    short8 qf[2][4];
#pragma unroll
    for (int mi = 0; mi < 2; ++mi)
#pragma unroll
      for (int ks = 0; ks < 4; ++ks)
        qf[mi][ks] = *(const short8*)&Qr[qbase + (size_t)(qb + w * 32 + mi * 16 + lr) * HD + ks * 32 + lg * 8];

    float m2[2][4];
    f32x4 oacc[2][8], osum[2];
#pragma unroll
    for (int mi = 0; mi < 2; ++mi) {
#pragma unroll
      for (int v = 0; v < 4; ++v) m2[mi][v] = -INFINITY;
#pragma unroll
      for (int nd = 0; nd < 8; ++nd) oacc[mi][nd] = (f32x4){0.f, 0.f, 0.f, 0.f};
      osum[mi] = (f32x4){0.f, 0.f, 0.f, 0.f};
    }

    STAGE(0, 0);
    __syncthreads();  // drains vmcnt -> buf0 ready
    int cur = 0;

    for (int t = 0; t < ntiles; ++t) {
      const int kt = t * 64;
      if (t + 1 < ntiles) STAGE(cur ^ 1, kt + 64);  // prefetch under compute

      // ---- scores = Q K^T  (from Kl[cur])
      f32x4 sc[2][4];
#pragma unroll
      for (int mi = 0; mi < 2; ++mi)
#pragma unroll
        for (int ni = 0; ni < 4; ++ni) sc[mi][ni] = (f32x4){0.f, 0.f, 0.f, 0.f};
#pragma unroll
      for (int ks = 0; ks < 4; ++ks) {
        short8 kf[4];
#pragma unroll
        for (int ni = 0; ni < 4; ++ni) {
          int row = ni * 16 + lr;
          int ch = ks * 4 + lg;
          int chs = (ch & 8) | ((ch ^ row) & 7);
          kf[ni] = *(const short8*)&Kl[cur][row * 128 + chs * 8];
        }
#pragma unroll
        for (int mi = 0; mi < 2; ++mi)
#pragma unroll
          for (int ni = 0; ni < 4; ++ni)
            sc[mi][ni] = __builtin_amdgcn_mfma_f32_16x16x32_bf16(qf[mi][ks], kf[ni], sc[mi][ni], 0, 0, 0);
      }

      // ---- scale to log2 domain, mask, row max
      const bool edge = (kt + 64 > qb);
      float rm[2][4];
#pragma unroll
      for (int mi = 0; mi < 2; ++mi)
#pragma unroll
        for (int v = 0; v < 4; ++v) {
          const int q_abs = qb + w * 32 + mi * 16 + lg * 4 + v;
          float rmax = -INFINITY;
#pragma unroll
          for (int ni = 0; ni < 4; ++ni) {
            float s = sc[mi][ni][v] * scl;
            if (edge && (kt + ni * 16 + lr > q_abs)) s = -INFINITY;
            sc[mi][ni][v] = s;
            rmax = fmaxf(rmax, s);
          }
          rmax = fmaxf(rmax, __shfl_xor(rmax, 1));
          rmax = fmaxf(rmax, __shfl_xor(rmax, 2));
          rmax = fmaxf(rmax, __shfl_xor(rmax, 4));
          rmax = fmaxf(rmax, __shfl_xor(rmax, 8));
          rm[mi][v] = rmax;
        }

      // ---- defer-max rescale (skip when growth <= 8 in log2 units)
      bool need = false;
#pragma unroll
      for (int mi = 0; mi < 2; ++mi)
#pragma unroll
        for (int v = 0; v < 4; ++v) need |= (rm[mi][v] > m2[mi][v] + 8.0f);
      if (__any(need)) {
#pragma unroll
        for (int mi = 0; mi < 2; ++mi)
#pragma unroll
          for (int v = 0; v < 4; ++v) {
            const float mnew = fmaxf(m2[mi][v], rm[mi][v]);
            const float fr = exp2f(m2[mi][v] - mnew);
            m2[mi][v] = mnew;
            osum[mi][v] *= fr;
#pragma unroll
            for (int nd = 0; nd < 8; ++nd) oacc[mi][nd][v] *= fr;
          }
      }

      // ---- P = exp2(s - m), store bf16 to per-wave LDS
#pragma unroll
      for (int mi = 0; mi < 2; ++mi)
#pragma unroll
        for (int v = 0; v < 4; ++v) {
          const int prow = mi * 16 + lg * 4 + v;
          const float mv = m2[mi][v];
#pragma unroll
          for (int ni = 0; ni < 4; ++ni) {
            float p = exp2f(sc[mi][ni][v] - mv);
            int col = ni * 16 + lr;
            Pl[w * 2048 + prow * 64 + (((col >> 3) ^ prow) & 7) * 8 + (col & 7)] = f2bf(p);
          }
        }
      asm volatile("s_waitcnt lgkmcnt(0)" ::: "memory");

      // ---- O += P V  and  sum += P * ones (from Vl[cur])
#pragma unroll
      for (int ks = 0; ks < 2; ++ks) {
        short8 pf[2];
#pragma unroll
        for (int mi = 0; mi < 2; ++mi) {
          int row = mi * 16 + lr;
          int ch = ks * 4 + lg;
          pf[mi] = *(const short8*)&Pl[w * 2048 + row * 64 + ((ch ^ row) & 7) * 8];
        }
#pragma unroll
        for (int mi = 0; mi < 2; ++mi)
          osum[mi] = __builtin_amdgcn_mfma_f32_16x16x32_bf16(pf[mi], onesv, osum[mi], 0, 0, 0);
#pragma unroll
        for (int nd = 0; nd < 8; ++nd) {
          int rowv = nd * 16 + lr;
          int ch = ks * 4 + lg;
          short8 vf = *(const short8*)&Vl[cur][rowv * 64 + ((ch ^ rowv) & 7) * 8];
#pragma unroll
          for (int mi = 0; mi < 2; ++mi)
            oacc[mi][nd] = __builtin_amdgcn_mfma_f32_16x16x32_bf16(pf[mi], vf, oacc[mi][nd], 0, 0, 0);
        }
      }
      __syncthreads();  // drains vmcnt -> next buffer staged; all waves done with cur
      cur ^= 1;
    }

    // ---- epilogue: O /= sum, write bf16 token-major [b*S+q][h*128+d]
#pragma unroll
    for (int mi = 0; mi < 2; ++mi)
#pragma unroll
      for (int v = 0; v < 4; ++v) {
        const int q_abs = qb + w * 32 + mi * 16 + lg * 4 + v;
        const float inv = 1.f / osum[mi][v];
#pragma unroll
        for (int nd = 0; nd < 8; ++nd) {
          int d = nd * 16 + lr;
          Ao[((size_t)(b * S_ + q_abs)) * D_ + h * HD + d] = f2bf(oacc[mi][nd][v] * inv);
        }
      }
  }
#undef STAGE
}

// ---------------- host launch ----------------
extern "C" void kernel_launch(void* const* d_in, const int* in_sizes, int n_in,
                              void* d_out, int out_size, void* d_ws, size_t ws_size,
                              hipStream_t stream) {
  const float* x  = (const float*)d_in[0];
  const float* wq = (const float*)d_in[1];
  const float* wk = (const float*)d_in[2];
  const float* wv = (const float*)d_in[3];
  const float* wo = (const float*)d_in[4];
  const float* fc = (const float*)d_in[5];
  const float* fs = (const float*)d_in[6];

  const size_t SZ_X  = (size_t)B_ * S_ * D_ * 2;
  const size_t SZ_WQ = (size_t)D_ * D_ * 2;
  const size_t SZ_WK = (size_t)NKV * HD * D_ * 2;
  char* ws = (char*)d_ws;
  u16* Xb  = (u16*)(ws);
  u16* Wqb = (u16*)(ws + SZ_X);
  u16* Wkb = (u16*)(ws + SZ_X + SZ_WQ);
  u16* Wvb = (u16*)(ws + SZ_X + SZ_WQ + SZ_WK);
  u16* Wob = (u16*)(ws + SZ_X + SZ_WQ + 2 * SZ_WK);
  u16* Qr  = (u16*)(ws + SZ_X + 2 * SZ_WQ + 2 * SZ_WK);
  u16* Kr  = (u16*)(ws + 2 * SZ_X + 2 * SZ_WQ + 2 * SZ_WK);
  u16* Vt  = (u16*)(ws + 2 * SZ_X + 2 * SZ_WQ + 3 * SZ_WK);
  u16* Ao  = (u16*)(ws + 2 * SZ_X + 2 * SZ_WQ + 4 * SZ_WK);
  const size_t NEEDED = 3 * SZ_X + 2 * SZ_WQ + 4 * SZ_WK;
  if (ws_size < NEEDED) return;

  const int nX = B_ * S_ * D_;
  const int nWQ = D_ * D_;
  const int nWK = NKV * HD * D_;
  f32_to_bf16_k<<<nX / 8 / 256, 256, 0, stream>>>(x, Xb, nX / 8);
  f32_to_bf16_k<<<nWQ / 8 / 256, 256, 0, stream>>>(wq, Wqb, nWQ / 8);
  f32_to_bf16_k<<<nWK / 8 / 256, 256, 0, stream>>>(wk, Wkb, nWK / 8);
  f32_to_bf16_k<<<nWK / 8 / 256, 256, 0, stream>>>(wv, Wvb, nWK / 8);
  f32_to_bf16_k<<<nWQ / 8 / 256, 256, 0, stream>>>(wo, Wob, nWQ / 8);

  gemm_bt<1><<<dim3(D_ / 128, (B_ * S_) / 128), 256, 0, stream>>>(Xb, Wqb, Qr, B_ * S_, D_, D_, NH);
  gemm_bt<1><<<dim3((NKV * HD) / 128, (B_ * S_) / 128), 256, 0, stream>>>(Xb, Wkb, Kr, B_ * S_, NKV * HD, D_, NKV);
  gemm_bt<2><<<dim3((NKV * HD) / 128, (B_ * S_) / 128), 256, 0, stream>>>(Xb, Wvb, Vt, B_ * S_, NKV * HD, D_, NKV);

  const int qChunks = B_ * NH * S_ * (HD / 8);
  const int kChunks = B_ * NKV * S_ * (HD / 8);
  rope_k<<<qChunks / 256, 256, 0, stream>>>(Qr, fc, fs, qChunks);
  rope_k<<<kChunks / 256, 256, 0, stream>>>(Kr, fc, fs, kChunks);

  attn_k<<<dim3(8, NH, B_), 256, 0, stream>>>(Qr, Kr, Vt, Ao);

  gemm_bt<0><<<dim3(D_ / 128, (B_ * S_) / 128), 256, 0, stream>>>(Ao, Wob, d_out, B_ * S_, D_, D_, 0);
}

// Round 3
// 755.806 us; speedup vs baseline: 1.5384x; 1.1984x over previous
//
#include <hip/hip_runtime.h>
#include <cstdint>
#include <cstddef>

#define B_  2
#define S_  2048
#define D_  4096
#define NH  32
#define NKV 8
#define HD  128

typedef unsigned short u16;
typedef unsigned int   u32;
typedef __attribute__((ext_vector_type(8))) short short8;
typedef __attribute__((ext_vector_type(4))) float f32x4;

__device__ __forceinline__ u16 f2bf(float f) {
  u32 u = __float_as_uint(f);
  u32 r = (u + 0x7FFFu + ((u >> 16) & 1u)) >> 16;  // RNE
  return (u16)r;
}
__device__ __forceinline__ float bf2f(u32 lo16) {
  return __uint_as_float(lo16 << 16);
}
__device__ __forceinline__ u32 cvtpk_bf16(float lo, float hi) {
  u32 r;
  asm("v_cvt_pk_bf16_f32 %0, %1, %2" : "=v"(r) : "v"(lo), "v"(hi));
  return r;
}
__device__ __forceinline__ void load_lds16(const void* g, void* lds) {
  __builtin_amdgcn_global_load_lds(
      (const __attribute__((address_space(1))) u32*)g,
      (__attribute__((address_space(3))) u32*)lds, 16, 0, 0);
}

// ---------------- fp32 -> bf16 converter (8 elems/thread) ----------------
__global__ __launch_bounds__(256) void f32_to_bf16_k(const float* __restrict__ src,
                                                     u16* __restrict__ dst, int n8) {
  int i = blockIdx.x * 256 + threadIdx.x;
  if (i >= n8) return;
  const float4* s = (const float4*)src + (size_t)i * 2;
  float4 a = s[0], b = s[1];
  u32 w0 = (u32)f2bf(a.x) | ((u32)f2bf(a.y) << 16);
  u32 w1 = (u32)f2bf(a.z) | ((u32)f2bf(a.w) << 16);
  u32 w2 = (u32)f2bf(b.x) | ((u32)f2bf(b.y) << 16);
  u32 w3 = (u32)f2bf(b.z) | ((u32)f2bf(b.w) << 16);
  uint4 o; o.x = w0; o.y = w1; o.z = w2; o.w = w3;
  *((uint4*)dst + i) = o;
}

// ---------------- RoPE in-place on [BH][S][128] bf16 ----------------
__global__ __launch_bounds__(256) void rope_k(u16* __restrict__ t,
                                              const float* __restrict__ ct,
                                              const float* __restrict__ st, int nchunks) {
  int i = blockIdx.x * 256 + threadIdx.x;
  if (i >= nchunks) return;
  int j8 = i & 15;            // which 8-elem chunk within the 128-d row
  int s  = (i >> 4) & (S_ - 1);
  uint4 v = *((uint4*)t + i);
  float4 c  = *(const float4*)(ct + (size_t)s * 64 + j8 * 4);
  float4 sn = *(const float4*)(st + (size_t)s * 64 + j8 * 4);
  u32 w[4] = {v.x, v.y, v.z, v.w};
  float cc[4] = {c.x, c.y, c.z, c.w};
  float ss[4] = {sn.x, sn.y, sn.z, sn.w};
#pragma unroll
  for (int j = 0; j < 4; ++j) {
    float e = bf2f(w[j] & 0xffffu), o = bf2f(w[j] >> 16);
    float e2 = e * cc[j] - o * ss[j];
    float o2 = e * ss[j] + o * cc[j];
    w[j] = (u32)f2bf(e2) | ((u32)f2bf(o2) << 16);
  }
  uint4 ov; ov.x = w[0]; ov.y = w[1]; ov.z = w[2]; ov.w = w[3];
  *((uint4*)t + i) = ov;
}

// ---------------- GEMM: C[m,n] = sum_k A[m,k]*Bw[n,k] (both row-major bf16) ---
template <int MODE>
__global__ __launch_bounds__(256)
void gemm_bt(const u16* __restrict__ A, const u16* __restrict__ Bw,
             void* __restrict__ Cout, int M, int N, int K, int Hh) {
  const int tid = threadIdx.x;
  const int lid = tid & 63, w = tid >> 6;
  const int lr = lid & 15, lg = lid >> 4;
  const int wm = w >> 1, wn = w & 1;
  const int bm = blockIdx.y * 128, bn = blockIdx.x * 128;
  __shared__ __align__(16) u16 Al[128 * 64];
  __shared__ __align__(16) u16 Bl[128 * 64];
  f32x4 acc[4][4];
#pragma unroll
  for (int i = 0; i < 4; ++i)
#pragma unroll
    for (int j = 0; j < 4; ++j) acc[i][j] = (f32x4){0.f, 0.f, 0.f, 0.f};

  const int rowst = tid >> 3;   // + i*32
  const int cbst  = tid & 7;

  for (int k0 = 0; k0 < K; k0 += 64) {
    __syncthreads();
#pragma unroll
    for (int i = 0; i < 4; ++i) {
      int row = i * 32 + rowst;
      load_lds16(A + (size_t)(bm + row) * K + k0 + cbst * 8, &Al[(i * 256 + w * 64) * 8]);
    }
#pragma unroll
    for (int i = 0; i < 4; ++i) {
      int row = i * 32 + rowst;
      load_lds16(Bw + (size_t)(bn + row) * K + k0 + cbst * 8, &Bl[(i * 256 + w * 64) * 8]);
    }
    __syncthreads();
#pragma unroll
    for (int ks = 0; ks < 2; ++ks) {
      short8 af[4], bf[4];
#pragma unroll
      for (int mi = 0; mi < 4; ++mi)
        af[mi] = *(const short8*)&Al[(wm * 64 + mi * 16 + lr) * 64 + ks * 32 + lg * 8];
#pragma unroll
      for (int ni = 0; ni < 4; ++ni)
        bf[ni] = *(const short8*)&Bl[(wn * 64 + ni * 16 + lr) * 64 + ks * 32 + lg * 8];
#pragma unroll
      for (int mi = 0; mi < 4; ++mi)
#pragma unroll
        for (int ni = 0; ni < 4; ++ni)
          acc[mi][ni] = __builtin_amdgcn_mfma_f32_16x16x32_bf16(af[mi], bf[ni], acc[mi][ni], 0, 0, 0);
    }
  }
#pragma unroll
  for (int mi = 0; mi < 4; ++mi)
#pragma unroll
    for (int ni = 0; ni < 4; ++ni)
#pragma unroll
      for (int v = 0; v < 4; ++v) {
        int m = bm + wm * 64 + mi * 16 + lg * 4 + v;
        int n = bn + wn * 64 + ni * 16 + lr;
        float val = acc[mi][ni][v];
        if (MODE == 0) {
          ((float*)Cout)[(size_t)m * N + n] = val;
        } else if (MODE == 1) {
          int b = m >> 11, s = m & (S_ - 1), hh = n >> 7, d = n & (HD - 1);
          ((u16*)Cout)[(((size_t)(b * Hh + hh)) * S_ + s) * HD + d] = f2bf(val);
        } else {
          int b = m >> 11, s = m & (S_ - 1), hh = n >> 7, d = n & (HD - 1);
          ((u16*)Cout)[(((size_t)(b * Hh + hh)) * HD + d) * S_ + s] = f2bf(val);
        }
      }
}

// ---------------- Flash attention, swapped-QK form ----------------
// Grid (8, NH, B), 512 threads (8 waves x 16 q-rows). Block x: q-tiles (15-x), (x).
// QK^T computed swapped: sc = mfma(K as A, Q as B) -> D[kv][q], q = lane&15.
// Softmax per-q is lane-local (in-lane max/sum + 2 shfl_xor). O accumulated
// transposed: oacc = mfma(V^T as A, P as B) -> D[d][q]; rescale is one scalar/lane.
// P goes through a tiny XOR-swizzled per-wave LDS region (8x b32 write, 2x b128 read).
__global__ __launch_bounds__(512, 4)
void attn_k(const u16* __restrict__ Qr, const u16* __restrict__ Kr,
            const u16* __restrict__ Vt, u16* __restrict__ Ao) {
  const int xp = blockIdx.x, h = blockIdx.y, b = blockIdx.z;
  const int kvh = h >> 2;
  const int tid = threadIdx.x, lid = tid & 63, w = tid >> 6;
  const int lr = lid & 15, lg = lid >> 4;
  __shared__ __align__(16) u16 Kl[2][64 * 128];   // [kv][d], XOR-swizzled 16B chunks
  __shared__ __align__(16) u16 Vl[2][128 * 64];   // [d][kv], XOR-swizzled
  __shared__ __align__(16) u32 Plw[8 * 512];      // per-wave 16q x 64kv bf16 as u32 words

  const size_t qbase = ((size_t)(b * NH + h)) * S_ * HD;
  const size_t kbase = ((size_t)(b * NKV + kvh)) * S_ * HD;
  const size_t vbase = ((size_t)(b * NKV + kvh)) * HD * S_;
  const float scl = 0.08838834764831845f * 1.44269504088896340f;  // log2e/sqrt(128)
  const int pb = w * 512 + lr * 32;   // per-wave P base (u32 words), row = q = lr
  const int qx = 4 * (lr & 7);        // P-word XOR swizzle

#define STAGE(BUF, KT)                                                              \
  do {                                                                              \
    _Pragma("unroll")                                                               \
    for (int i_ = 0; i_ < 2; ++i_) {                                                \
      int c_ = i_ * 512 + tid;                                                      \
      int row_ = c_ >> 4, cb_ = c_ & 15;                                            \
      int cbs_ = (cb_ & 8) | ((cb_ ^ row_) & 7);                                    \
      load_lds16(&Kr[kbase + (size_t)((KT) + row_) * HD + cbs_ * 8],                \
                 &Kl[BUF][(i_ * 512 + w * 64) * 8]);                                \
    }                                                                               \
    _Pragma("unroll")                                                               \
    for (int i_ = 0; i_ < 2; ++i_) {                                                \
      int c_ = i_ * 512 + tid;                                                      \
      int d_ = c_ >> 3, cb_ = c_ & 7;                                               \
      int cbs_ = (cb_ ^ d_) & 7;                                                    \
      load_lds16(&Vt[vbase + (size_t)d_ * S_ + (KT) + cbs_ * 8],                    \
                 &Vl[BUF][(i_ * 512 + w * 64) * 8]);                                \
    }                                                                               \
  } while (0)

  for (int part = 0; part < 2; ++part) {
    const int qi = part ? xp : (15 - xp);
    const int qb = qi * 128;
    const int ntiles = qi * 2 + 2;
    const int q_abs = qb + w * 16 + lr;

    // Q fragments (as B operand): lane holds Q[q = qb+16w+lr][d = 32ks+8lg..+7]
    short8 qf[4];
#pragma unroll
    for (int ks = 0; ks < 4; ++ks)
      qf[ks] = *(const short8*)&Qr[qbase + (size_t)q_abs * HD + ks * 32 + lg * 8];

    float m2 = -3.0e38f, osum = 0.f;
    f32x4 oacc[8];
#pragma unroll
    for (int nd = 0; nd < 8; ++nd) oacc[nd] = (f32x4){0.f, 0.f, 0.f, 0.f};

    STAGE(0, 0);
    __syncthreads();  // drains vmcnt -> buf0 ready
    int cur = 0;

    for (int t = 0; t < ntiles; ++t) {
      const int kt = t * 64;
      if (t + 1 < ntiles) STAGE(cur ^ 1, kt + 64);  // prefetch under compute

      // ---- sc[ni] = K Q^T   (D[kv][q]: q = lr, kv = 16ni + 4lg + v)
      f32x4 sc[4];
#pragma unroll
      for (int ni = 0; ni < 4; ++ni) sc[ni] = (f32x4){0.f, 0.f, 0.f, 0.f};
#pragma unroll
      for (int ks = 0; ks < 4; ++ks) {
#pragma unroll
        for (int ni = 0; ni < 4; ++ni) {
          int row = ni * 16 + lr;
          int ch = ks * 4 + lg;
          int chs = (ch & 8) | ((ch ^ row) & 7);
          short8 kf = *(const short8*)&Kl[cur][row * 128 + chs * 8];
          sc[ni] = __builtin_amdgcn_mfma_f32_16x16x32_bf16(kf, qf[ks], sc[ni], 0, 0, 0);
        }
      }

      // ---- scale to log2 domain, causal mask, in-lane row max
      const bool edge = (kt + 64 > qb);
      float mx = -3.0e38f;
#pragma unroll
      for (int ni = 0; ni < 4; ++ni)
#pragma unroll
        for (int v = 0; v < 4; ++v) {
          float s = sc[ni][v] * scl;
          int kv = kt + ni * 16 + lg * 4 + v;
          if (edge && kv > q_abs) s = -3.0e38f;
          sc[ni][v] = s;
          mx = fmaxf(mx, s);
        }
      mx = fmaxf(mx, __shfl_xor(mx, 16));
      mx = fmaxf(mx, __shfl_xor(mx, 32));

      // ---- defer-max rescale (skip when growth <= 8 in log2 units)
      if (__any(mx > m2 + 8.0f)) {
        float mnew = fmaxf(m2, mx);
        float fr = exp2f(m2 - mnew);
        m2 = mnew;
        osum *= fr;
#pragma unroll
        for (int nd = 0; nd < 8; ++nd) oacc[nd] *= fr;
      }

      // ---- P = exp2(s - m): pack pairs, 8 swizzled b32 writes; in-lane sum
      float ps = 0.f;
#pragma unroll
      for (int ni = 0; ni < 4; ++ni) {
#pragma unroll
        for (int p = 0; p < 2; ++p) {
          float e0 = exp2f(sc[ni][2 * p] - m2);
          float e1 = exp2f(sc[ni][2 * p + 1] - m2);
          ps += e0 + e1;
          Plw[pb + ((8 * ni + 2 * lg + p) ^ qx)] = cvtpk_bf16(e0, e1);
        }
      }
      osum += ps;

      asm volatile("s_waitcnt lgkmcnt(0)" ::: "memory");  // own-wave P writes landed
      __builtin_amdgcn_sched_barrier(0);

      // ---- O^T += V^T P^T : oacc[nd] cols q = lr, rows d = 16nd + 4lg + v
#pragma unroll
      for (int ks = 0; ks < 2; ++ks) {
        short8 pfk = *(const short8*)&Plw[pb + ((16 * ks + 4 * lg) ^ qx)];
#pragma unroll
        for (int nd = 0; nd < 8; ++nd) {
          int rowv = nd * 16 + lr;
          int ch = ks * 4 + lg;
          short8 vf = *(const short8*)&Vl[cur][rowv * 64 + ((ch ^ rowv) & 7) * 8];
          oacc[nd] = __builtin_amdgcn_mfma_f32_16x16x32_bf16(vf, pfk, oacc[nd], 0, 0, 0);
        }
      }
      __syncthreads();  // drains vmcnt -> next buffer staged; all waves done with cur
      cur ^= 1;
    }

    // ---- epilogue: reduce sum across lane groups, O /= sum, write bf16
    float os = osum;
    os += __shfl_xor(os, 16);
    os += __shfl_xor(os, 32);
    const float inv = 1.0f / os;
    const size_t orow = ((size_t)(b * S_ + q_abs)) * D_ + h * HD;
    u32* AoW = (u32*)Ao;
#pragma unroll
    for (int nd = 0; nd < 8; ++nd) {
#pragma unroll
      for (int p = 0; p < 2; ++p) {
        u32 pk = cvtpk_bf16(oacc[nd][2 * p] * inv, oacc[nd][2 * p + 1] * inv);
        AoW[(orow + nd * 16 + lg * 4 + 2 * p) >> 1] = pk;
      }
    }
  }
#undef STAGE
}

// ---------------- host launch ----------------
extern "C" void kernel_launch(void* const* d_in, const int* in_sizes, int n_in,
                              void* d_out, int out_size, void* d_ws, size_t ws_size,
                              hipStream_t stream) {
  const float* x  = (const float*)d_in[0];
  const float* wq = (const float*)d_in[1];
  const float* wk = (const float*)d_in[2];
  const float* wv = (const float*)d_in[3];
  const float* wo = (const float*)d_in[4];
  const float* fc = (const float*)d_in[5];
  const float* fs = (const float*)d_in[6];

  const size_t SZ_X  = (size_t)B_ * S_ * D_ * 2;
  const size_t SZ_WQ = (size_t)D_ * D_ * 2;
  const size_t SZ_WK = (size_t)NKV * HD * D_ * 2;
  char* ws = (char*)d_ws;
  u16* Xb  = (u16*)(ws);
  u16* Wqb = (u16*)(ws + SZ_X);
  u16* Wkb = (u16*)(ws + SZ_X + SZ_WQ);
  u16* Wvb = (u16*)(ws + SZ_X + SZ_WQ + SZ_WK);
  u16* Wob = (u16*)(ws + SZ_X + SZ_WQ + 2 * SZ_WK);
  u16* Qr  = (u16*)(ws + SZ_X + 2 * SZ_WQ + 2 * SZ_WK);
  u16* Kr  = (u16*)(ws + 2 * SZ_X + 2 * SZ_WQ + 2 * SZ_WK);
  u16* Vt  = (u16*)(ws + 2 * SZ_X + 2 * SZ_WQ + 3 * SZ_WK);
  u16* Ao  = (u16*)(ws + 2 * SZ_X + 2 * SZ_WQ + 4 * SZ_WK);
  const size_t NEEDED = 3 * SZ_X + 2 * SZ_WQ + 4 * SZ_WK;
  if (ws_size < NEEDED) return;

  const int nX = B_ * S_ * D_;
  const int nWQ = D_ * D_;
  const int nWK = NKV * HD * D_;
  f32_to_bf16_k<<<nX / 8 / 256, 256, 0, stream>>>(x, Xb, nX / 8);
  f32_to_bf16_k<<<nWQ / 8 / 256, 256, 0, stream>>>(wq, Wqb, nWQ / 8);
  f32_to_bf16_k<<<nWK / 8 / 256, 256, 0, stream>>>(wk, Wkb, nWK / 8);
  f32_to_bf16_k<<<nWK / 8 / 256, 256, 0, stream>>>(wv, Wvb, nWK / 8);
  f32_to_bf16_k<<<nWQ / 8 / 256, 256, 0, stream>>>(wo, Wob, nWQ / 8);

  gemm_bt<1><<<dim3(D_ / 128, (B_ * S_) / 128), 256, 0, stream>>>(Xb, Wqb, Qr, B_ * S_, D_, D_, NH);
  gemm_bt<1><<<dim3((NKV * HD) / 128, (B_ * S_) / 128), 256, 0, stream>>>(Xb, Wkb, Kr, B_ * S_, NKV * HD, D_, NKV);
  gemm_bt<2><<<dim3((NKV * HD) / 128, (B_ * S_) / 128), 256, 0, stream>>>(Xb, Wvb, Vt, B_ * S_, NKV * HD, D_, NKV);

  const int qChunks = B_ * NH * S_ * (HD / 8);
  const int kChunks = B_ * NKV * S_ * (HD / 8);
  rope_k<<<qChunks / 256, 256, 0, stream>>>(Qr, fc, fs, qChunks);
  rope_k<<<kChunks / 256, 256, 0, stream>>>(Kr, fc, fs, kChunks);

  attn_k<<<dim3(8, NH, B_), 512, 0, stream>>>(Qr, Kr, Vt, Ao);

  gemm_bt<0><<<dim3(D_ / 128, (B_ * S_) / 128), 256, 0, stream>>>(Ao, Wob, d_out, B_ * S_, D_, D_, 0);
}

// Round 4
// 676.201 us; speedup vs baseline: 1.7196x; 1.1177x over previous
//
#include <hip/hip_runtime.h>
#include <cstdint>
#include <cstddef>

#define B_  2
#define S_  2048
#define D_  4096
#define NH  32
#define NKV 8
#define HD  128

typedef unsigned short u16;
typedef unsigned int   u32;
typedef __attribute__((ext_vector_type(8))) short short8;
typedef __attribute__((ext_vector_type(4))) float f32x4;

__device__ __forceinline__ u16 f2bf(float f) {
  u32 u = __float_as_uint(f);
  u32 r = (u + 0x7FFFu + ((u >> 16) & 1u)) >> 16;  // RNE
  return (u16)r;
}
__device__ __forceinline__ float bf2f(u32 lo16) {
  return __uint_as_float(lo16 << 16);
}
__device__ __forceinline__ u32 cvtpk_bf16(float lo, float hi) {
  u32 r;
  asm("v_cvt_pk_bf16_f32 %0, %1, %2" : "=v"(r) : "v"(lo), "v"(hi));
  return r;
}
__device__ __forceinline__ void load_lds16(const void* g, void* lds) {
  __builtin_amdgcn_global_load_lds(
      (const __attribute__((address_space(1))) u32*)g,
      (__attribute__((address_space(3))) u32*)lds, 16, 0, 0);
}

// ---------------- fp32 -> bf16 converter (8 elems/thread) ----------------
__global__ __launch_bounds__(256) void f32_to_bf16_k(const float* __restrict__ src,
                                                     u16* __restrict__ dst, int n8) {
  int i = blockIdx.x * 256 + threadIdx.x;
  if (i >= n8) return;
  const float4* s = (const float4*)src + (size_t)i * 2;
  float4 a = s[0], b = s[1];
  u32 w0 = (u32)f2bf(a.x) | ((u32)f2bf(a.y) << 16);
  u32 w1 = (u32)f2bf(a.z) | ((u32)f2bf(a.w) << 16);
  u32 w2 = (u32)f2bf(b.x) | ((u32)f2bf(b.y) << 16);
  u32 w3 = (u32)f2bf(b.z) | ((u32)f2bf(b.w) << 16);
  uint4 o; o.x = w0; o.y = w1; o.z = w2; o.w = w3;
  *((uint4*)dst + i) = o;
}

// ---------------- GEMM: C[m,n] = sum_k A[m,k]*Bw[n,k] (both row-major bf16) ---
// LDS tiles XOR-swizzled at 16B-chunk granularity (G21: inverse-swizzled global
// source + swizzled ds_read slot; LDS linear for global_load_lds).
// MODE 0: fp32 row-major C[M][N]
// MODE 1: bf16 -> [b][h][s][128]  (optionally fused RoPE on the fp32 acc)
// MODE 2: bf16 -> [b][h][d][s]    (V transposed)
template <int MODE, bool ROPE>
__global__ __launch_bounds__(256)
void gemm_bt(const u16* __restrict__ A, const u16* __restrict__ Bw,
             void* __restrict__ Cout, int M, int N, int K, int Hh,
             const float* __restrict__ fc, const float* __restrict__ fs) {
  const int tid = threadIdx.x;
  const int lid = tid & 63, w = tid >> 6;
  const int lr = lid & 15, lg = lid >> 4;
  const int wm = w >> 1, wn = w & 1;

  // T1: bijective XCD swizzle (grids here always have nwg % 8 == 0)
  const int gx = gridDim.x;
  const int nwg = gx * gridDim.y;
  const int lin = blockIdx.y * gx + blockIdx.x;
  const int cpx = nwg >> 3;
  const int lin2 = (lin & 7) * cpx + (lin >> 3);
  const int bm = (lin2 / gx) * 128, bn = (lin2 % gx) * 128;

  __shared__ __align__(16) u16 Al[128 * 64];
  __shared__ __align__(16) u16 Bl[128 * 64];
  f32x4 acc[4][4];
#pragma unroll
  for (int i = 0; i < 4; ++i)
#pragma unroll
    for (int j = 0; j < 4; ++j) acc[i][j] = (f32x4){0.f, 0.f, 0.f, 0.f};

  for (int k0 = 0; k0 < K; k0 += 64) {
    __syncthreads();
#pragma unroll
    for (int i = 0; i < 4; ++i) {
      int c = i * 256 + tid;            // LDS chunk id 0..1023
      int row = c >> 3, cb = c & 7;
      int cbs = (cb ^ row) & 7;         // inverse-swizzled global chunk
      load_lds16(A + (size_t)(bm + row) * K + k0 + cbs * 8, &Al[c * 8]);
    }
#pragma unroll
    for (int i = 0; i < 4; ++i) {
      int c = i * 256 + tid;
      int row = c >> 3, cb = c & 7;
      int cbs = (cb ^ row) & 7;
      load_lds16(Bw + (size_t)(bn + row) * K + k0 + cbs * 8, &Bl[c * 8]);
    }
    __syncthreads();
#pragma unroll
    for (int ks = 0; ks < 2; ++ks) {
      short8 af[4], bf[4];
#pragma unroll
      for (int mi = 0; mi < 4; ++mi) {
        int row = wm * 64 + mi * 16 + lr;
        af[mi] = *(const short8*)&Al[row * 64 + (((ks * 4 + lg) ^ row) & 7) * 8];
      }
#pragma unroll
      for (int ni = 0; ni < 4; ++ni) {
        int row = wn * 64 + ni * 16 + lr;
        bf[ni] = *(const short8*)&Bl[row * 64 + (((ks * 4 + lg) ^ row) & 7) * 8];
      }
#pragma unroll
      for (int mi = 0; mi < 4; ++mi)
#pragma unroll
        for (int ni = 0; ni < 4; ++ni)
          acc[mi][ni] = __builtin_amdgcn_mfma_f32_16x16x32_bf16(af[mi], bf[ni], acc[mi][ni], 0, 0, 0);
    }
  }
#pragma unroll
  for (int mi = 0; mi < 4; ++mi)
#pragma unroll
    for (int ni = 0; ni < 4; ++ni)
#pragma unroll
      for (int v = 0; v < 4; ++v) {
        int m = bm + wm * 64 + mi * 16 + lg * 4 + v;
        int n = bn + wn * 64 + ni * 16 + lr;
        float val = acc[mi][ni][v];
        if (ROPE) {
          // pairs (2j, 2j+1) live on adjacent lanes (n and n^1)
          int srow = m & (S_ - 1);
          int j = (n & (HD - 1)) >> 1;
          float c = fc[(size_t)srow * 64 + j];
          float s = fs[(size_t)srow * 64 + j];
          float partner = __shfl_xor(val, 1);
          val = (n & 1) ? (val * c + partner * s) : (val * c - partner * s);
        }
        if (MODE == 0) {
          ((float*)Cout)[(size_t)m * N + n] = val;
        } else if (MODE == 1) {
          int b = m >> 11, s = m & (S_ - 1), hh = n >> 7, d = n & (HD - 1);
          ((u16*)Cout)[(((size_t)(b * Hh + hh)) * S_ + s) * HD + d] = f2bf(val);
        } else {
          int b = m >> 11, s = m & (S_ - 1), hh = n >> 7, d = n & (HD - 1);
          ((u16*)Cout)[(((size_t)(b * Hh + hh)) * HD + d) * S_ + s] = f2bf(val);
        }
      }
}

// ---------------- Flash attention, swapped-QK form ----------------
// Grid (8, NH, B), 512 threads (8 waves x 16 q-rows). Block x: q-tiles (15-x), (x).
__global__ __launch_bounds__(512, 4)
void attn_k(const u16* __restrict__ Qr, const u16* __restrict__ Kr,
            const u16* __restrict__ Vt, u16* __restrict__ Ao) {
  const int xp = blockIdx.x, h = blockIdx.y, b = blockIdx.z;
  const int kvh = h >> 2;
  const int tid = threadIdx.x, lid = tid & 63, w = tid >> 6;
  const int lr = lid & 15, lg = lid >> 4;
  __shared__ __align__(16) u16 Kl[2][64 * 128];   // [kv][d], XOR-swizzled 16B chunks
  __shared__ __align__(16) u16 Vl[2][128 * 64];   // [d][kv], XOR-swizzled
  __shared__ __align__(16) u32 Plw[8 * 512];      // per-wave 16q x 64kv bf16 as u32 words

  const size_t qbase = ((size_t)(b * NH + h)) * S_ * HD;
  const size_t kbase = ((size_t)(b * NKV + kvh)) * S_ * HD;
  const size_t vbase = ((size_t)(b * NKV + kvh)) * HD * S_;
  const float scl = 0.08838834764831845f * 1.44269504088896340f;  // log2e/sqrt(128)
  const int pb = w * 512 + lr * 32;   // per-wave P base (u32 words), row = q = lr
  const int qx = 4 * (lr & 7);        // P-word XOR swizzle

#define STAGE(BUF, KT)                                                              \
  do {                                                                              \
    _Pragma("unroll")                                                               \
    for (int i_ = 0; i_ < 2; ++i_) {                                                \
      int c_ = i_ * 512 + tid;                                                      \
      int row_ = c_ >> 4, cb_ = c_ & 15;                                            \
      int cbs_ = (cb_ & 8) | ((cb_ ^ row_) & 7);                                    \
      load_lds16(&Kr[kbase + (size_t)((KT) + row_) * HD + cbs_ * 8],                \
                 &Kl[BUF][(i_ * 512 + w * 64) * 8]);                                \
    }                                                                               \
    _Pragma("unroll")                                                               \
    for (int i_ = 0; i_ < 2; ++i_) {                                                \
      int c_ = i_ * 512 + tid;                                                      \
      int d_ = c_ >> 3, cb_ = c_ & 7;                                               \
      int cbs_ = (cb_ ^ d_) & 7;                                                    \
      load_lds16(&Vt[vbase + (size_t)d_ * S_ + (KT) + cbs_ * 8],                    \
                 &Vl[BUF][(i_ * 512 + w * 64) * 8]);                                \
    }                                                                               \
  } while (0)

  for (int part = 0; part < 2; ++part) {
    const int qi = part ? xp : (15 - xp);
    const int qb = qi * 128;
    const int ntiles = qi * 2 + 2;
    const int q_abs = qb + w * 16 + lr;

    // Q fragments (as B operand): lane holds Q[q = qb+16w+lr][d = 32ks+8lg..+7]
    short8 qf[4];
#pragma unroll
    for (int ks = 0; ks < 4; ++ks)
      qf[ks] = *(const short8*)&Qr[qbase + (size_t)q_abs * HD + ks * 32 + lg * 8];

    float m2 = -3.0e38f, osum = 0.f;
    f32x4 oacc[8];
#pragma unroll
    for (int nd = 0; nd < 8; ++nd) oacc[nd] = (f32x4){0.f, 0.f, 0.f, 0.f};

    STAGE(0, 0);
    __syncthreads();  // drains vmcnt -> buf0 ready
    int cur = 0;

    for (int t = 0; t < ntiles; ++t) {
      const int kt = t * 64;
      if (t + 1 < ntiles) STAGE(cur ^ 1, kt + 64);  // prefetch under compute

      // ---- sc[ni] = K Q^T   (D[kv][q]: q = lr, kv = 16ni + 4lg + v)
      f32x4 sc[4];
#pragma unroll
      for (int ni = 0; ni < 4; ++ni) sc[ni] = (f32x4){0.f, 0.f, 0.f, 0.f};
      __builtin_amdgcn_s_setprio(1);
#pragma unroll
      for (int ks = 0; ks < 4; ++ks) {
#pragma unroll
        for (int ni = 0; ni < 4; ++ni) {
          int row = ni * 16 + lr;
          int ch = ks * 4 + lg;
          int chs = (ch & 8) | ((ch ^ row) & 7);
          short8 kf = *(const short8*)&Kl[cur][row * 128 + chs * 8];
          sc[ni] = __builtin_amdgcn_mfma_f32_16x16x32_bf16(kf, qf[ks], sc[ni], 0, 0, 0);
        }
      }
      __builtin_amdgcn_s_setprio(0);

      // ---- scale to log2 domain, causal mask, in-lane row max
      const bool edge = (kt + 64 > qb);
      float mx = -3.0e38f;
#pragma unroll
      for (int ni = 0; ni < 4; ++ni)
#pragma unroll
        for (int v = 0; v < 4; ++v) {
          float s = sc[ni][v] * scl;
          int kv = kt + ni * 16 + lg * 4 + v;
          if (edge && kv > q_abs) s = -3.0e38f;
          sc[ni][v] = s;
          mx = fmaxf(mx, s);
        }
      mx = fmaxf(mx, __shfl_xor(mx, 16));
      mx = fmaxf(mx, __shfl_xor(mx, 32));

      // ---- defer-max rescale (skip when growth <= 8 in log2 units)
      if (__any(mx > m2 + 8.0f)) {
        float mnew = fmaxf(m2, mx);
        float fr = exp2f(m2 - mnew);
        m2 = mnew;
        osum *= fr;
#pragma unroll
        for (int nd = 0; nd < 8; ++nd) oacc[nd] *= fr;
      }

      // ---- P = exp2(s - m): pack pairs, 8 swizzled b32 writes; in-lane sum
      float ps = 0.f;
#pragma unroll
      for (int ni = 0; ni < 4; ++ni) {
#pragma unroll
        for (int p = 0; p < 2; ++p) {
          float e0 = exp2f(sc[ni][2 * p] - m2);
          float e1 = exp2f(sc[ni][2 * p + 1] - m2);
          ps += e0 + e1;
          Plw[pb + ((8 * ni + 2 * lg + p) ^ qx)] = cvtpk_bf16(e0, e1);
        }
      }
      osum += ps;

      asm volatile("s_waitcnt lgkmcnt(0)" ::: "memory");  // own-wave P writes landed
      __builtin_amdgcn_sched_barrier(0);

      // ---- O^T += V^T P^T : oacc[nd] cols q = lr, rows d = 16nd + 4lg + v
      __builtin_amdgcn_s_setprio(1);
#pragma unroll
      for (int ks = 0; ks < 2; ++ks) {
        short8 pfk = *(const short8*)&Plw[pb + ((16 * ks + 4 * lg) ^ qx)];
#pragma unroll
        for (int nd = 0; nd < 8; ++nd) {
          int rowv = nd * 16 + lr;
          int ch = ks * 4 + lg;
          short8 vf = *(const short8*)&Vl[cur][rowv * 64 + ((ch ^ rowv) & 7) * 8];
          oacc[nd] = __builtin_amdgcn_mfma_f32_16x16x32_bf16(vf, pfk, oacc[nd], 0, 0, 0);
        }
      }
      __builtin_amdgcn_s_setprio(0);
      __syncthreads();  // drains vmcnt -> next buffer staged; all waves done with cur
      cur ^= 1;
    }

    // ---- epilogue: reduce sum across lane groups, O /= sum, write bf16
    float os = osum;
    os += __shfl_xor(os, 16);
    os += __shfl_xor(os, 32);
    const float inv = 1.0f / os;
    const size_t orow = ((size_t)(b * S_ + q_abs)) * D_ + h * HD;
    u32* AoW = (u32*)Ao;
#pragma unroll
    for (int nd = 0; nd < 8; ++nd) {
#pragma unroll
      for (int p = 0; p < 2; ++p) {
        u32 pk = cvtpk_bf16(oacc[nd][2 * p] * inv, oacc[nd][2 * p + 1] * inv);
        AoW[(orow + nd * 16 + lg * 4 + 2 * p) >> 1] = pk;
      }
    }
  }
#undef STAGE
}

// ---------------- host launch ----------------
extern "C" void kernel_launch(void* const* d_in, const int* in_sizes, int n_in,
                              void* d_out, int out_size, void* d_ws, size_t ws_size,
                              hipStream_t stream) {
  const float* x  = (const float*)d_in[0];
  const float* wq = (const float*)d_in[1];
  const float* wk = (const float*)d_in[2];
  const float* wv = (const float*)d_in[3];
  const float* wo = (const float*)d_in[4];
  const float* fc = (const float*)d_in[5];
  const float* fs = (const float*)d_in[6];

  const size_t SZ_X  = (size_t)B_ * S_ * D_ * 2;
  const size_t SZ_WQ = (size_t)D_ * D_ * 2;
  const size_t SZ_WK = (size_t)NKV * HD * D_ * 2;
  char* ws = (char*)d_ws;
  u16* Xb  = (u16*)(ws);
  u16* Wqb = (u16*)(ws + SZ_X);
  u16* Wkb = (u16*)(ws + SZ_X + SZ_WQ);
  u16* Wvb = (u16*)(ws + SZ_X + SZ_WQ + SZ_WK);
  u16* Wob = (u16*)(ws + SZ_X + SZ_WQ + 2 * SZ_WK);
  u16* Qr  = (u16*)(ws + SZ_X + 2 * SZ_WQ + 2 * SZ_WK);
  u16* Kr  = (u16*)(ws + 2 * SZ_X + 2 * SZ_WQ + 2 * SZ_WK);
  u16* Vt  = (u16*)(ws + 2 * SZ_X + 2 * SZ_WQ + 3 * SZ_WK);
  u16* Ao  = (u16*)(ws + 2 * SZ_X + 2 * SZ_WQ + 4 * SZ_WK);
  const size_t NEEDED = 3 * SZ_X + 2 * SZ_WQ + 4 * SZ_WK;
  if (ws_size < NEEDED) return;

  const int nX = B_ * S_ * D_;
  const int nWQ = D_ * D_;
  const int nWK = NKV * HD * D_;
  f32_to_bf16_k<<<nX / 8 / 256, 256, 0, stream>>>(x, Xb, nX / 8);
  f32_to_bf16_k<<<nWQ / 8 / 256, 256, 0, stream>>>(wq, Wqb, nWQ / 8);
  f32_to_bf16_k<<<nWK / 8 / 256, 256, 0, stream>>>(wk, Wkb, nWK / 8);
  f32_to_bf16_k<<<nWK / 8 / 256, 256, 0, stream>>>(wv, Wvb, nWK / 8);
  f32_to_bf16_k<<<nWQ / 8 / 256, 256, 0, stream>>>(wo, Wob, nWQ / 8);

  // Q/K projections with fused RoPE in the epilogue (fp32 acc precision)
  gemm_bt<1, true><<<dim3(D_ / 128, (B_ * S_) / 128), 256, 0, stream>>>(
      Xb, Wqb, Qr, B_ * S_, D_, D_, NH, fc, fs);
  gemm_bt<1, true><<<dim3((NKV * HD) / 128, (B_ * S_) / 128), 256, 0, stream>>>(
      Xb, Wkb, Kr, B_ * S_, NKV * HD, D_, NKV, fc, fs);
  gemm_bt<2, false><<<dim3((NKV * HD) / 128, (B_ * S_) / 128), 256, 0, stream>>>(
      Xb, Wvb, Vt, B_ * S_, NKV * HD, D_, NKV, nullptr, nullptr);

  attn_k<<<dim3(8, NH, B_), 512, 0, stream>>>(Qr, Kr, Vt, Ao);

  gemm_bt<0, false><<<dim3(D_ / 128, (B_ * S_) / 128), 256, 0, stream>>>(
      Ao, Wob, d_out, B_ * S_, D_, D_, 0, nullptr, nullptr);
}

// Round 5
// 599.004 us; speedup vs baseline: 1.9412x; 1.1289x over previous
//
#include <hip/hip_runtime.h>
#include <cstdint>
#include <cstddef>

#define B_  2
#define S_  2048
#define D_  4096
#define NH  32
#define NKV 8
#define HD  128

typedef unsigned short u16;
typedef unsigned int   u32;
typedef __attribute__((ext_vector_type(8))) short short8;
typedef __attribute__((ext_vector_type(4))) float f32x4;

__device__ __forceinline__ u16 f2bf(float f) {
  u32 u = __float_as_uint(f);
  u32 r = (u + 0x7FFFu + ((u >> 16) & 1u)) >> 16;  // RNE
  return (u16)r;
}
__device__ __forceinline__ float bf2f(u32 lo16) {
  return __uint_as_float(lo16 << 16);
}
__device__ __forceinline__ u32 cvtpk_bf16(float lo, float hi) {
  u32 r;
  asm("v_cvt_pk_bf16_f32 %0, %1, %2" : "=v"(r) : "v"(lo), "v"(hi));
  return r;
}
__device__ __forceinline__ void load_lds16(const void* g, void* lds) {
  __builtin_amdgcn_global_load_lds(
      (const __attribute__((address_space(1))) u32*)g,
      (__attribute__((address_space(3))) u32*)lds, 16, 0, 0);
}

// ---------------- fp32 -> bf16 converter (8 elems/thread) ----------------
__global__ __launch_bounds__(256) void f32_to_bf16_k(const float* __restrict__ src,
                                                     u16* __restrict__ dst, int n8) {
  int i = blockIdx.x * 256 + threadIdx.x;
  if (i >= n8) return;
  const float4* s = (const float4*)src + (size_t)i * 2;
  float4 a = s[0], b = s[1];
  u32 w0 = (u32)f2bf(a.x) | ((u32)f2bf(a.y) << 16);
  u32 w1 = (u32)f2bf(a.z) | ((u32)f2bf(a.w) << 16);
  u32 w2 = (u32)f2bf(b.x) | ((u32)f2bf(b.y) << 16);
  u32 w3 = (u32)f2bf(b.z) | ((u32)f2bf(b.w) << 16);
  uint4 o; o.x = w0; o.y = w1; o.z = w2; o.w = w3;
  *((uint4*)dst + i) = o;
}

// ================= 256^2 tile, 4-phase/K-tile counted-vmcnt GEMM =================
// C[m,n] = sum_k A[m,k]*Bw[n,k], row-major bf16. 512 thr = 8 waves (2M x 4N).
// LDS: [2 dbuf][2 k-half][256 rows][32 cols] for A and B = 128 KiB.
// Half-tile = one k-half of one matrix = 4 loads/thread. Per phase: ds_read frags,
// issue 2 global_load_lds for next tile, barrier, 16 MFMA (setprio). vmcnt(4) at
// mid-tile and tile-end keeps one half-tile in flight (counted, never drain-0).
template <int MODE, bool ROPE>
__global__ __launch_bounds__(512, 2)
void gemm256(const u16* __restrict__ A, const u16* __restrict__ Bw,
             void* __restrict__ Cout, int M, int N, int K, int Hh,
             const float* __restrict__ fc, const float* __restrict__ fs) {
  const int tid = threadIdx.x, lid = tid & 63, w = tid >> 6;
  const int lr = lid & 15, lg = lid >> 4;
  const int wm = w >> 2, wn = w & 3;

  // chunked XCD swizzle for the 16x16 grid: XCD gets a 4bm x 8bn block
  int lin = blockIdx.y * gridDim.x + blockIdx.x;
  int bm, bn;
  if (gridDim.x == 16 && gridDim.y == 16) {
    int xcd = lin & 7, idx = lin >> 3;
    bm = ((xcd & 3) * 4 + (idx >> 3)) * 256;
    bn = ((xcd >> 2) * 8 + (idx & 7)) * 256;
  } else {
    bm = blockIdx.y * 256;
    bn = blockIdx.x * 256;
  }

  __shared__ __align__(16) u16 Al[2][2][8192];  // [buf][khalf][row*32 + slot*8]
  __shared__ __align__(16) u16 Bl[2][2][8192];

  f32x4 acc[8][4];
#pragma unroll
  for (int i = 0; i < 8; ++i)
#pragma unroll
    for (int j = 0; j < 4; ++j) acc[i][j] = (f32x4){0.f, 0.f, 0.f, 0.f};

  // staging constants (loop-invariant): thread handles chunks c = tid, tid+512
  // chunk c -> row = c>>2, cb = c&3; swizzled source chunk = cb ^ ((row>>1)&3)

#define STG_A(B2, KS, K0)                                                       \
  do {                                                                          \
    _Pragma("unroll")                                                           \
    for (int j_ = 0; j_ < 2; ++j_) {                                            \
      int c_ = j_ * 512 + tid;                                                  \
      int r_ = c_ >> 2, cb_ = c_ & 3;                                           \
      int s_ = (cb_ ^ (r_ >> 1)) & 3;                                           \
      load_lds16(A + (size_t)(bm + r_) * K + (K0) + (KS) * 32 + s_ * 8,         \
                 &Al[B2][KS][c_ * 8]);                                          \
    }                                                                           \
  } while (0)
#define STG_B(B2, KS, K0)                                                       \
  do {                                                                          \
    _Pragma("unroll")                                                           \
    for (int j_ = 0; j_ < 2; ++j_) {                                            \
      int c_ = j_ * 512 + tid;                                                  \
      int r_ = c_ >> 2, cb_ = c_ & 3;                                           \
      int s_ = (cb_ ^ (r_ >> 1)) & 3;                                           \
      load_lds16(Bw + (size_t)(bn + r_) * K + (K0) + (KS) * 32 + s_ * 8,        \
                 &Bl[B2][KS][c_ * 8]);                                          \
    }                                                                           \
  } while (0)

  const int nt = K >> 6;
  // prologue: tile 0, halves 0 then 1 (8 loads); wait all but newest half-tile
  STG_A(0, 0, 0); STG_B(0, 0, 0); STG_A(0, 1, 0); STG_B(0, 1, 0);
  asm volatile("s_waitcnt vmcnt(4)" ::: "memory");
  __builtin_amdgcn_s_barrier();

  for (int t = 0; t < nt; ++t) {
    const int buf = t & 1, b2 = buf ^ 1;
    const int k1 = (t + 1) << 6;
    const bool pf = (t + 1 < nt);
    short8 a[4], bfr[4];

    // ---- phase 1: ks=0, m-frags 0-3, all B-frags
#pragma unroll
    for (int ni = 0; ni < 4; ++ni) {
      int r = wn * 64 + ni * 16 + lr;
      bfr[ni] = *(const short8*)&Bl[buf][0][r * 32 + ((lg ^ (r >> 1)) & 3) * 8];
    }
#pragma unroll
    for (int mi = 0; mi < 4; ++mi) {
      int r = wm * 128 + mi * 16 + lr;
      a[mi] = *(const short8*)&Al[buf][0][r * 32 + ((lg ^ (r >> 1)) & 3) * 8];
    }
    if (pf) STG_A(b2, 0, k1);
    __builtin_amdgcn_s_barrier();
    __builtin_amdgcn_s_setprio(1);
#pragma unroll
    for (int mi = 0; mi < 4; ++mi)
#pragma unroll
      for (int ni = 0; ni < 4; ++ni)
        acc[mi][ni] = __builtin_amdgcn_mfma_f32_16x16x32_bf16(a[mi], bfr[ni], acc[mi][ni], 0, 0, 0);
    __builtin_amdgcn_s_setprio(0);

    // ---- phase 2: ks=0, m-frags 4-7 (B reused from regs)
#pragma unroll
    for (int mi = 0; mi < 4; ++mi) {
      int r = wm * 128 + (mi + 4) * 16 + lr;
      a[mi] = *(const short8*)&Al[buf][0][r * 32 + ((lg ^ (r >> 1)) & 3) * 8];
    }
    if (pf) STG_B(b2, 0, k1);
    __builtin_amdgcn_s_barrier();
    __builtin_amdgcn_s_setprio(1);
#pragma unroll
    for (int mi = 0; mi < 4; ++mi)
#pragma unroll
      for (int ni = 0; ni < 4; ++ni)
        acc[mi + 4][ni] = __builtin_amdgcn_mfma_f32_16x16x32_bf16(a[mi], bfr[ni], acc[mi + 4][ni], 0, 0, 0);
    __builtin_amdgcn_s_setprio(0);

    // ---- mid-tile wait: current tile's k-half 1 must be landed (all waves)
    if (pf) asm volatile("s_waitcnt vmcnt(4)" ::: "memory");
    else    asm volatile("s_waitcnt vmcnt(0)" ::: "memory");
    __builtin_amdgcn_s_barrier();

    // ---- phase 3: ks=1, m-frags 0-3
#pragma unroll
    for (int ni = 0; ni < 4; ++ni) {
      int r = wn * 64 + ni * 16 + lr;
      bfr[ni] = *(const short8*)&Bl[buf][1][r * 32 + ((lg ^ (r >> 1)) & 3) * 8];
    }
#pragma unroll
    for (int mi = 0; mi < 4; ++mi) {
      int r = wm * 128 + mi * 16 + lr;
      a[mi] = *(const short8*)&Al[buf][1][r * 32 + ((lg ^ (r >> 1)) & 3) * 8];
    }
    if (pf) STG_A(b2, 1, k1);
    __builtin_amdgcn_s_barrier();
    __builtin_amdgcn_s_setprio(1);
#pragma unroll
    for (int mi = 0; mi < 4; ++mi)
#pragma unroll
      for (int ni = 0; ni < 4; ++ni)
        acc[mi][ni] = __builtin_amdgcn_mfma_f32_16x16x32_bf16(a[mi], bfr[ni], acc[mi][ni], 0, 0, 0);
    __builtin_amdgcn_s_setprio(0);

    // ---- phase 4: ks=1, m-frags 4-7
#pragma unroll
    for (int mi = 0; mi < 4; ++mi) {
      int r = wm * 128 + (mi + 4) * 16 + lr;
      a[mi] = *(const short8*)&Al[buf][1][r * 32 + ((lg ^ (r >> 1)) & 3) * 8];
    }
    if (pf) STG_B(b2, 1, k1);
    __builtin_amdgcn_s_barrier();
    __builtin_amdgcn_s_setprio(1);
#pragma unroll
    for (int mi = 0; mi < 4; ++mi)
#pragma unroll
      for (int ni = 0; ni < 4; ++ni)
        acc[mi + 4][ni] = __builtin_amdgcn_mfma_f32_16x16x32_bf16(a[mi], bfr[ni], acc[mi + 4][ni], 0, 0, 0);
    __builtin_amdgcn_s_setprio(0);

    // ---- tile-end wait: next tile's k-half 0 landed before next iteration
    if (pf) {
      asm volatile("s_waitcnt vmcnt(4)" ::: "memory");
      __builtin_amdgcn_s_barrier();
    }
  }
#undef STG_A
#undef STG_B

  // ---- epilogue
#pragma unroll
  for (int mi = 0; mi < 8; ++mi)
#pragma unroll
    for (int ni = 0; ni < 4; ++ni)
#pragma unroll
      for (int v = 0; v < 4; ++v) {
        int m = bm + wm * 128 + mi * 16 + lg * 4 + v;
        int n = bn + wn * 64 + ni * 16 + lr;
        float val = acc[mi][ni][v];
        if (ROPE) {
          int srow = m & (S_ - 1);
          int j = (n & (HD - 1)) >> 1;
          float c = fc[(size_t)srow * 64 + j];
          float s = fs[(size_t)srow * 64 + j];
          float partner = __shfl_xor(val, 1);
          val = (n & 1) ? (val * c + partner * s) : (val * c - partner * s);
        }
        if (MODE == 0) {
          ((float*)Cout)[(size_t)m * N + n] = val;
        } else if (MODE == 1) {
          int b = m >> 11, s = m & (S_ - 1), hh = n >> 7, d = n & (HD - 1);
          ((u16*)Cout)[(((size_t)(b * Hh + hh)) * S_ + s) * HD + d] = f2bf(val);
        } else {
          int b = m >> 11, s = m & (S_ - 1), hh = n >> 7, d = n & (HD - 1);
          ((u16*)Cout)[(((size_t)(b * Hh + hh)) * HD + d) * S_ + s] = f2bf(val);
        }
      }
}

// ---------------- 128^2 GEMM (2-phase) for the narrow K/V projections ----------
template <int MODE, bool ROPE>
__global__ __launch_bounds__(256)
void gemm_bt(const u16* __restrict__ A, const u16* __restrict__ Bw,
             void* __restrict__ Cout, int M, int N, int K, int Hh,
             const float* __restrict__ fc, const float* __restrict__ fs) {
  const int tid = threadIdx.x;
  const int lid = tid & 63, w = tid >> 6;
  const int lr = lid & 15, lg = lid >> 4;
  const int wm = w >> 1, wn = w & 1;

  const int gx = gridDim.x;
  const int nwg = gx * gridDim.y;
  const int lin = blockIdx.y * gx + blockIdx.x;
  const int cpx = nwg >> 3;
  const int lin2 = (lin & 7) * cpx + (lin >> 3);
  const int bm = (lin2 / gx) * 128, bn = (lin2 % gx) * 128;

  __shared__ __align__(16) u16 Al[128 * 64];
  __shared__ __align__(16) u16 Bl[128 * 64];
  f32x4 acc[4][4];
#pragma unroll
  for (int i = 0; i < 4; ++i)
#pragma unroll
    for (int j = 0; j < 4; ++j) acc[i][j] = (f32x4){0.f, 0.f, 0.f, 0.f};

  for (int k0 = 0; k0 < K; k0 += 64) {
    __syncthreads();
#pragma unroll
    for (int i = 0; i < 4; ++i) {
      int c = i * 256 + tid;
      int row = c >> 3, cb = c & 7;
      int cbs = (cb ^ row) & 7;
      load_lds16(A + (size_t)(bm + row) * K + k0 + cbs * 8, &Al[c * 8]);
    }
#pragma unroll
    for (int i = 0; i < 4; ++i) {
      int c = i * 256 + tid;
      int row = c >> 3, cb = c & 7;
      int cbs = (cb ^ row) & 7;
      load_lds16(Bw + (size_t)(bn + row) * K + k0 + cbs * 8, &Bl[c * 8]);
    }
    __syncthreads();
#pragma unroll
    for (int ks = 0; ks < 2; ++ks) {
      short8 af[4], bf[4];
#pragma unroll
      for (int mi = 0; mi < 4; ++mi) {
        int row = wm * 64 + mi * 16 + lr;
        af[mi] = *(const short8*)&Al[row * 64 + (((ks * 4 + lg) ^ row) & 7) * 8];
      }
#pragma unroll
      for (int ni = 0; ni < 4; ++ni) {
        int row = wn * 64 + ni * 16 + lr;
        bf[ni] = *(const short8*)&Bl[row * 64 + (((ks * 4 + lg) ^ row) & 7) * 8];
      }
#pragma unroll
      for (int mi = 0; mi < 4; ++mi)
#pragma unroll
        for (int ni = 0; ni < 4; ++ni)
          acc[mi][ni] = __builtin_amdgcn_mfma_f32_16x16x32_bf16(af[mi], bf[ni], acc[mi][ni], 0, 0, 0);
    }
  }
#pragma unroll
  for (int mi = 0; mi < 4; ++mi)
#pragma unroll
    for (int ni = 0; ni < 4; ++ni)
#pragma unroll
      for (int v = 0; v < 4; ++v) {
        int m = bm + wm * 64 + mi * 16 + lg * 4 + v;
        int n = bn + wn * 64 + ni * 16 + lr;
        float val = acc[mi][ni][v];
        if (ROPE) {
          int srow = m & (S_ - 1);
          int j = (n & (HD - 1)) >> 1;
          float c = fc[(size_t)srow * 64 + j];
          float s = fs[(size_t)srow * 64 + j];
          float partner = __shfl_xor(val, 1);
          val = (n & 1) ? (val * c + partner * s) : (val * c - partner * s);
        }
        if (MODE == 0) {
          ((float*)Cout)[(size_t)m * N + n] = val;
        } else if (MODE == 1) {
          int b = m >> 11, s = m & (S_ - 1), hh = n >> 7, d = n & (HD - 1);
          ((u16*)Cout)[(((size_t)(b * Hh + hh)) * S_ + s) * HD + d] = f2bf(val);
        } else {
          int b = m >> 11, s = m & (S_ - 1), hh = n >> 7, d = n & (HD - 1);
          ((u16*)Cout)[(((size_t)(b * Hh + hh)) * HD + d) * S_ + s] = f2bf(val);
        }
      }
}

// ---------------- Flash attention, swapped-QK form ----------------
__global__ __launch_bounds__(512, 4)
void attn_k(const u16* __restrict__ Qr, const u16* __restrict__ Kr,
            const u16* __restrict__ Vt, u16* __restrict__ Ao) {
  const int xp = blockIdx.x, h = blockIdx.y, b = blockIdx.z;
  const int kvh = h >> 2;
  const int tid = threadIdx.x, lid = tid & 63, w = tid >> 6;
  const int lr = lid & 15, lg = lid >> 4;
  __shared__ __align__(16) u16 Kl[2][64 * 128];
  __shared__ __align__(16) u16 Vl[2][128 * 64];
  __shared__ __align__(16) u32 Plw[8 * 512];

  const size_t qbase = ((size_t)(b * NH + h)) * S_ * HD;
  const size_t kbase = ((size_t)(b * NKV + kvh)) * S_ * HD;
  const size_t vbase = ((size_t)(b * NKV + kvh)) * HD * S_;
  const float scl = 0.08838834764831845f * 1.44269504088896340f;
  const int pb = w * 512 + lr * 32;
  const int qx = 4 * (lr & 7);

#define STAGE(BUF, KT)                                                              \
  do {                                                                              \
    _Pragma("unroll")                                                               \
    for (int i_ = 0; i_ < 2; ++i_) {                                                \
      int c_ = i_ * 512 + tid;                                                      \
      int row_ = c_ >> 4, cb_ = c_ & 15;                                            \
      int cbs_ = (cb_ & 8) | ((cb_ ^ row_) & 7);                                    \
      load_lds16(&Kr[kbase + (size_t)((KT) + row_) * HD + cbs_ * 8],                \
                 &Kl[BUF][(i_ * 512 + w * 64) * 8]);                                \
    }                                                                               \
    _Pragma("unroll")                                                               \
    for (int i_ = 0; i_ < 2; ++i_) {                                                \
      int c_ = i_ * 512 + tid;                                                      \
      int d_ = c_ >> 3, cb_ = c_ & 7;                                               \
      int cbs_ = (cb_ ^ d_) & 7;                                                    \
      load_lds16(&Vt[vbase + (size_t)d_ * S_ + (KT) + cbs_ * 8],                    \
                 &Vl[BUF][(i_ * 512 + w * 64) * 8]);                                \
    }                                                                               \
  } while (0)

  for (int part = 0; part < 2; ++part) {
    const int qi = part ? xp : (15 - xp);
    const int qb = qi * 128;
    const int ntiles = qi * 2 + 2;
    const int q_abs = qb + w * 16 + lr;

    short8 qf[4];
#pragma unroll
    for (int ks = 0; ks < 4; ++ks)
      qf[ks] = *(const short8*)&Qr[qbase + (size_t)q_abs * HD + ks * 32 + lg * 8];

    float m2 = -3.0e38f, osum = 0.f;
    f32x4 oacc[8];
#pragma unroll
    for (int nd = 0; nd < 8; ++nd) oacc[nd] = (f32x4){0.f, 0.f, 0.f, 0.f};

    STAGE(0, 0);
    __syncthreads();
    int cur = 0;

    for (int t = 0; t < ntiles; ++t) {
      const int kt = t * 64;
      if (t + 1 < ntiles) STAGE(cur ^ 1, kt + 64);

      f32x4 sc[4];
#pragma unroll
      for (int ni = 0; ni < 4; ++ni) sc[ni] = (f32x4){0.f, 0.f, 0.f, 0.f};
      __builtin_amdgcn_s_setprio(1);
#pragma unroll
      for (int ks = 0; ks < 4; ++ks) {
#pragma unroll
        for (int ni = 0; ni < 4; ++ni) {
          int row = ni * 16 + lr;
          int ch = ks * 4 + lg;
          int chs = (ch & 8) | ((ch ^ row) & 7);
          short8 kf = *(const short8*)&Kl[cur][row * 128 + chs * 8];
          sc[ni] = __builtin_amdgcn_mfma_f32_16x16x32_bf16(kf, qf[ks], sc[ni], 0, 0, 0);
        }
      }
      __builtin_amdgcn_s_setprio(0);

      const bool edge = (kt + 64 > qb);
      float mx = -3.0e38f;
#pragma unroll
      for (int ni = 0; ni < 4; ++ni)
#pragma unroll
        for (int v = 0; v < 4; ++v) {
          float s = sc[ni][v] * scl;
          int kv = kt + ni * 16 + lg * 4 + v;
          if (edge && kv > q_abs) s = -3.0e38f;
          sc[ni][v] = s;
          mx = fmaxf(mx, s);
        }
      mx = fmaxf(mx, __shfl_xor(mx, 16));
      mx = fmaxf(mx, __shfl_xor(mx, 32));

      if (__any(mx > m2 + 8.0f)) {
        float mnew = fmaxf(m2, mx);
        float fr = exp2f(m2 - mnew);
        m2 = mnew;
        osum *= fr;
#pragma unroll
        for (int nd = 0; nd < 8; ++nd) oacc[nd] *= fr;
      }

      float ps = 0.f;
#pragma unroll
      for (int ni = 0; ni < 4; ++ni) {
#pragma unroll
        for (int p = 0; p < 2; ++p) {
          float e0 = exp2f(sc[ni][2 * p] - m2);
          float e1 = exp2f(sc[ni][2 * p + 1] - m2);
          ps += e0 + e1;
          Plw[pb + ((8 * ni + 2 * lg + p) ^ qx)] = cvtpk_bf16(e0, e1);
        }
      }
      osum += ps;

      asm volatile("s_waitcnt lgkmcnt(0)" ::: "memory");
      __builtin_amdgcn_sched_barrier(0);

      __builtin_amdgcn_s_setprio(1);
#pragma unroll
      for (int ks = 0; ks < 2; ++ks) {
        short8 pfk = *(const short8*)&Plw[pb + ((16 * ks + 4 * lg) ^ qx)];
#pragma unroll
        for (int nd = 0; nd < 8; ++nd) {
          int rowv = nd * 16 + lr;
          int ch = ks * 4 + lg;
          short8 vf = *(const short8*)&Vl[cur][rowv * 64 + ((ch ^ rowv) & 7) * 8];
          oacc[nd] = __builtin_amdgcn_mfma_f32_16x16x32_bf16(vf, pfk, oacc[nd], 0, 0, 0);
        }
      }
      __builtin_amdgcn_s_setprio(0);
      __syncthreads();
      cur ^= 1;
    }

    float os = osum;
    os += __shfl_xor(os, 16);
    os += __shfl_xor(os, 32);
    const float inv = 1.0f / os;
    const size_t orow = ((size_t)(b * S_ + q_abs)) * D_ + h * HD;
    u32* AoW = (u32*)Ao;
#pragma unroll
    for (int nd = 0; nd < 8; ++nd) {
#pragma unroll
      for (int p = 0; p < 2; ++p) {
        u32 pk = cvtpk_bf16(oacc[nd][2 * p] * inv, oacc[nd][2 * p + 1] * inv);
        AoW[(orow + nd * 16 + lg * 4 + 2 * p) >> 1] = pk;
      }
    }
  }
#undef STAGE
}

// ---------------- host launch ----------------
extern "C" void kernel_launch(void* const* d_in, const int* in_sizes, int n_in,
                              void* d_out, int out_size, void* d_ws, size_t ws_size,
                              hipStream_t stream) {
  const float* x  = (const float*)d_in[0];
  const float* wq = (const float*)d_in[1];
  const float* wk = (const float*)d_in[2];
  const float* wv = (const float*)d_in[3];
  const float* wo = (const float*)d_in[4];
  const float* fc = (const float*)d_in[5];
  const float* fs = (const float*)d_in[6];

  const size_t SZ_X  = (size_t)B_ * S_ * D_ * 2;
  const size_t SZ_WQ = (size_t)D_ * D_ * 2;
  const size_t SZ_WK = (size_t)NKV * HD * D_ * 2;
  char* ws = (char*)d_ws;
  u16* Xb  = (u16*)(ws);
  u16* Wqb = (u16*)(ws + SZ_X);
  u16* Wkb = (u16*)(ws + SZ_X + SZ_WQ);
  u16* Wvb = (u16*)(ws + SZ_X + SZ_WQ + SZ_WK);
  u16* Wob = (u16*)(ws + SZ_X + SZ_WQ + 2 * SZ_WK);
  u16* Qr  = (u16*)(ws + SZ_X + 2 * SZ_WQ + 2 * SZ_WK);
  u16* Kr  = (u16*)(ws + 2 * SZ_X + 2 * SZ_WQ + 2 * SZ_WK);
  u16* Vt  = (u16*)(ws + 2 * SZ_X + 2 * SZ_WQ + 3 * SZ_WK);
  u16* Ao  = (u16*)(ws + 2 * SZ_X + 2 * SZ_WQ + 4 * SZ_WK);
  const size_t NEEDED = 3 * SZ_X + 2 * SZ_WQ + 4 * SZ_WK;
  if (ws_size < NEEDED) return;

  const int nX = B_ * S_ * D_;
  const int nWQ = D_ * D_;
  const int nWK = NKV * HD * D_;
  f32_to_bf16_k<<<nX / 8 / 256, 256, 0, stream>>>(x, Xb, nX / 8);
  f32_to_bf16_k<<<nWQ / 8 / 256, 256, 0, stream>>>(wq, Wqb, nWQ / 8);
  f32_to_bf16_k<<<nWK / 8 / 256, 256, 0, stream>>>(wk, Wkb, nWK / 8);
  f32_to_bf16_k<<<nWK / 8 / 256, 256, 0, stream>>>(wv, Wvb, nWK / 8);
  f32_to_bf16_k<<<nWQ / 8 / 256, 256, 0, stream>>>(wo, Wob, nWQ / 8);

  // Q projection (4096x4096x4096) on the 256^2 pipelined kernel, fused RoPE
  gemm256<1, true><<<dim3(16, 16), 512, 0, stream>>>(
      Xb, Wqb, Qr, B_ * S_, D_, D_, NH, fc, fs);
  // K/V projections (N=1024) on the 128^2 kernel
  gemm_bt<1, true><<<dim3((NKV * HD) / 128, (B_ * S_) / 128), 256, 0, stream>>>(
      Xb, Wkb, Kr, B_ * S_, NKV * HD, D_, NKV, fc, fs);
  gemm_bt<2, false><<<dim3((NKV * HD) / 128, (B_ * S_) / 128), 256, 0, stream>>>(
      Xb, Wvb, Vt, B_ * S_, NKV * HD, D_, NKV, nullptr, nullptr);

  attn_k<<<dim3(8, NH, B_), 512, 0, stream>>>(Qr, Kr, Vt, Ao);

  // O projection (4096x4096x4096), fp32 output
  gemm256<0, false><<<dim3(16, 16), 512, 0, stream>>>(
      Ao, Wob, d_out, B_ * S_, D_, D_, 0, nullptr, nullptr);
}

// Round 6
// 522.787 us; speedup vs baseline: 2.2242x; 1.1458x over previous
//
#include <hip/hip_runtime.h>
#include <cstdint>
#include <cstddef>

#define B_  2
#define S_  2048
#define D_  4096
#define NH  32
#define NKV 8
#define HD  128

typedef unsigned short u16;
typedef unsigned int   u32;
typedef __attribute__((ext_vector_type(8))) short short8;
typedef __attribute__((ext_vector_type(4))) float f32x4;

__device__ __forceinline__ u16 f2bf(float f) {
  u32 u = __float_as_uint(f);
  u32 r = (u + 0x7FFFu + ((u >> 16) & 1u)) >> 16;  // RNE
  return (u16)r;
}
__device__ __forceinline__ float bf2f(u32 lo16) {
  return __uint_as_float(lo16 << 16);
}
__device__ __forceinline__ u32 cvtpk_bf16(float lo, float hi) {
  u32 r;
  asm("v_cvt_pk_bf16_f32 %0, %1, %2" : "=v"(r) : "v"(lo), "v"(hi));
  return r;
}
__device__ __forceinline__ void load_lds16(const void* g, void* lds) {
  __builtin_amdgcn_global_load_lds(
      (const __attribute__((address_space(1))) u32*)g,
      (__attribute__((address_space(3))) u32*)lds, 16, 0, 0);
}

// ---------------- fused fp32 -> bf16 converter for all 5 tensors ----------------
// chunk = 8 elems; ranges (in chunks): x 2097152 | wq 2097152 | wk 524288 | wv 524288 | wo 2097152
__global__ __launch_bounds__(256) void cvt_all(
    const float* __restrict__ x, const float* __restrict__ wq,
    const float* __restrict__ wk, const float* __restrict__ wv,
    const float* __restrict__ wo, u16* __restrict__ Xb, u16* __restrict__ Wqb,
    u16* __restrict__ Wkb, u16* __restrict__ Wvb, u16* __restrict__ Wob) {
  long i = (long)blockIdx.x * 256 + threadIdx.x;
  const float* src; u16* dst; long off;
  if (i < 2097152L)      { src = x;  dst = Xb;  off = i; }
  else if (i < 4194304L) { src = wq; dst = Wqb; off = i - 2097152L; }
  else if (i < 4718592L) { src = wk; dst = Wkb; off = i - 4194304L; }
  else if (i < 5242880L) { src = wv; dst = Wvb; off = i - 4718592L; }
  else                   { src = wo; dst = Wob; off = i - 5242880L; }
  const float4* s = (const float4*)src + off * 2;
  float4 a = s[0], b = s[1];
  uint4 o;
  o.x = (u32)f2bf(a.x) | ((u32)f2bf(a.y) << 16);
  o.y = (u32)f2bf(a.z) | ((u32)f2bf(a.w) << 16);
  o.z = (u32)f2bf(b.x) | ((u32)f2bf(b.y) << 16);
  o.w = (u32)f2bf(b.z) | ((u32)f2bf(b.w) << 16);
  *((uint4*)dst + off) = o;
}

// ================= 256^2 tile, 4-phase/K-tile counted-vmcnt GEMM =================
// Deep schedule: ph1->A(t+1,ks1), ph2->B(t+1,ks1), ph3->A(t+2,ks0), ph4->B(t+2,ks0).
// Steady state: 4 half-tiles (8 loads) in flight; vmcnt(8) at mid/end only.
// Oldest-needed load issued 4 phases (~1400 cyc) before its wait -> HBM latency hidden.
template <int MODE, bool ROPE>
__global__ __launch_bounds__(512, 2)
void gemm256(const u16* __restrict__ A, const u16* __restrict__ Bw,
             void* __restrict__ Cout, int M, int N, int K, int Hh,
             const float* __restrict__ fc, const float* __restrict__ fs) {
  const int tid = threadIdx.x, lid = tid & 63, w = tid >> 6;
  const int lr = lid & 15, lg = lid >> 4;
  const int wm = w >> 2, wn = w & 3;

  // chunked XCD swizzle for the 16x16 grid: XCD gets a 4bm x 8bn block
  int lin = blockIdx.y * gridDim.x + blockIdx.x;
  int bm, bn;
  if (gridDim.x == 16 && gridDim.y == 16) {
    int xcd = lin & 7, idx = lin >> 3;
    bm = ((xcd & 3) * 4 + (idx >> 3)) * 256;
    bn = ((xcd >> 2) * 8 + (idx & 7)) * 256;
  } else {
    bm = blockIdx.y * 256;
    bn = blockIdx.x * 256;
  }

  __shared__ __align__(16) u16 Al[2][2][8192];  // [buf][khalf][row*32 + slot*8]
  __shared__ __align__(16) u16 Bl[2][2][8192];

  f32x4 acc[8][4];
#pragma unroll
  for (int i = 0; i < 8; ++i)
#pragma unroll
    for (int j = 0; j < 4; ++j) acc[i][j] = (f32x4){0.f, 0.f, 0.f, 0.f};

#define STG_A(B2, KS, K0)                                                       \
  do {                                                                          \
    _Pragma("unroll")                                                           \
    for (int j_ = 0; j_ < 2; ++j_) {                                            \
      int c_ = j_ * 512 + tid;                                                  \
      int r_ = c_ >> 2, cb_ = c_ & 3;                                           \
      int s_ = (cb_ ^ (r_ >> 1)) & 3;                                           \
      load_lds16(A + (size_t)(bm + r_) * K + (K0) + (KS) * 32 + s_ * 8,         \
                 &Al[B2][KS][c_ * 8]);                                          \
    }                                                                           \
  } while (0)
#define STG_B(B2, KS, K0)                                                       \
  do {                                                                          \
    _Pragma("unroll")                                                           \
    for (int j_ = 0; j_ < 2; ++j_) {                                            \
      int c_ = j_ * 512 + tid;                                                  \
      int r_ = c_ >> 2, cb_ = c_ & 3;                                           \
      int s_ = (cb_ ^ (r_ >> 1)) & 3;                                           \
      load_lds16(Bw + (size_t)(bn + r_) * K + (K0) + (KS) * 32 + s_ * 8,        \
                 &Bl[B2][KS][c_ * 8]);                                          \
    }                                                                           \
  } while (0)

  const int nt = K >> 6;  // K = 4096 -> nt = 64 (nt >= 2 assumed)
  // prologue: 6 half-tiles = tile0 complete + tile1 ks0 (12 loads)
  STG_A(0, 0, 0); STG_B(0, 0, 0); STG_A(0, 1, 0); STG_B(0, 1, 0);
  STG_A(1, 0, 64); STG_B(1, 0, 64);
  asm volatile("s_waitcnt vmcnt(8)" ::: "memory");  // tile0 ks0 landed
  __builtin_amdgcn_s_barrier();

  for (int t = 0; t < nt; ++t) {
    const int buf = t & 1, bufN = buf ^ 1;
    const int k1 = (t + 1) << 6, k2 = (t + 2) << 6;
    const bool pf1 = (t + 1 < nt), pf2 = (t + 2 < nt);
    short8 a[4], bfr[4];

    // ---- phase 1: ks=0, m-frags 0-3, all B-frags; stage A(t+1, ks1)
#pragma unroll
    for (int ni = 0; ni < 4; ++ni) {
      int r = wn * 64 + ni * 16 + lr;
      bfr[ni] = *(const short8*)&Bl[buf][0][r * 32 + ((lg ^ (r >> 1)) & 3) * 8];
    }
#pragma unroll
    for (int mi = 0; mi < 4; ++mi) {
      int r = wm * 128 + mi * 16 + lr;
      a[mi] = *(const short8*)&Al[buf][0][r * 32 + ((lg ^ (r >> 1)) & 3) * 8];
    }
    if (pf1) STG_A(bufN, 1, k1);
    __builtin_amdgcn_s_barrier();
    __builtin_amdgcn_s_setprio(1);
#pragma unroll
    for (int mi = 0; mi < 4; ++mi)
#pragma unroll
      for (int ni = 0; ni < 4; ++ni)
        acc[mi][ni] = __builtin_amdgcn_mfma_f32_16x16x32_bf16(a[mi], bfr[ni], acc[mi][ni], 0, 0, 0);
    __builtin_amdgcn_s_setprio(0);

    // ---- phase 2: ks=0, m-frags 4-7; stage B(t+1, ks1)
#pragma unroll
    for (int mi = 0; mi < 4; ++mi) {
      int r = wm * 128 + (mi + 4) * 16 + lr;
      a[mi] = *(const short8*)&Al[buf][0][r * 32 + ((lg ^ (r >> 1)) & 3) * 8];
    }
    if (pf1) STG_B(bufN, 1, k1);
    __builtin_amdgcn_s_barrier();
    __builtin_amdgcn_s_setprio(1);
#pragma unroll
    for (int mi = 0; mi < 4; ++mi)
#pragma unroll
      for (int ni = 0; ni < 4; ++ni)
        acc[mi + 4][ni] = __builtin_amdgcn_mfma_f32_16x16x32_bf16(a[mi], bfr[ni], acc[mi + 4][ni], 0, 0, 0);
    __builtin_amdgcn_s_setprio(0);

    // ---- mid wait: tile t ks1 (issued ph1/ph2 of t-1, 4 phases ago) landed
    if (pf1) asm volatile("s_waitcnt vmcnt(8)" ::: "memory");
    else     asm volatile("s_waitcnt vmcnt(0)" ::: "memory");
    __builtin_amdgcn_s_barrier();

    // ---- phase 3: ks=1, m-frags 0-3; stage A(t+2, ks0) into freed Al[buf][0]
#pragma unroll
    for (int ni = 0; ni < 4; ++ni) {
      int r = wn * 64 + ni * 16 + lr;
      bfr[ni] = *(const short8*)&Bl[buf][1][r * 32 + ((lg ^ (r >> 1)) & 3) * 8];
    }
#pragma unroll
    for (int mi = 0; mi < 4; ++mi) {
      int r = wm * 128 + mi * 16 + lr;
      a[mi] = *(const short8*)&Al[buf][1][r * 32 + ((lg ^ (r >> 1)) & 3) * 8];
    }
    if (pf2) STG_A(buf, 0, k2);
    __builtin_amdgcn_s_barrier();
    __builtin_amdgcn_s_setprio(1);
#pragma unroll
    for (int mi = 0; mi < 4; ++mi)
#pragma unroll
      for (int ni = 0; ni < 4; ++ni)
        acc[mi][ni] = __builtin_amdgcn_mfma_f32_16x16x32_bf16(a[mi], bfr[ni], acc[mi][ni], 0, 0, 0);
    __builtin_amdgcn_s_setprio(0);

    // ---- phase 4: ks=1, m-frags 4-7; stage B(t+2, ks0) into freed Bl[buf][0]
#pragma unroll
    for (int mi = 0; mi < 4; ++mi) {
      int r = wm * 128 + (mi + 4) * 16 + lr;
      a[mi] = *(const short8*)&Al[buf][1][r * 32 + ((lg ^ (r >> 1)) & 3) * 8];
    }
    if (pf2) STG_B(buf, 0, k2);
    __builtin_amdgcn_s_barrier();
    __builtin_amdgcn_s_setprio(1);
#pragma unroll
    for (int mi = 0; mi < 4; ++mi)
#pragma unroll
      for (int ni = 0; ni < 4; ++ni)
        acc[mi + 4][ni] = __builtin_amdgcn_mfma_f32_16x16x32_bf16(a[mi], bfr[ni], acc[mi + 4][ni], 0, 0, 0);
    __builtin_amdgcn_s_setprio(0);

    // ---- end wait: tile t+1 ks0 (issued ph3/ph4 of t-1) landed
    if (pf1) {
      if (pf2) asm volatile("s_waitcnt vmcnt(8)" ::: "memory");
      else     asm volatile("s_waitcnt vmcnt(4)" ::: "memory");
      __builtin_amdgcn_s_barrier();
    }
  }
#undef STG_A
#undef STG_B

  // ---- epilogue
#pragma unroll
  for (int mi = 0; mi < 8; ++mi)
#pragma unroll
    for (int ni = 0; ni < 4; ++ni)
#pragma unroll
      for (int v = 0; v < 4; ++v) {
        int m = bm + wm * 128 + mi * 16 + lg * 4 + v;
        int n = bn + wn * 64 + ni * 16 + lr;
        float val = acc[mi][ni][v];
        if (ROPE) {
          int srow = m & (S_ - 1);
          int j = (n & (HD - 1)) >> 1;
          float c = fc[(size_t)srow * 64 + j];
          float s = fs[(size_t)srow * 64 + j];
          float partner = __shfl_xor(val, 1);
          val = (n & 1) ? (val * c + partner * s) : (val * c - partner * s);
        }
        if (MODE == 0) {
          ((float*)Cout)[(size_t)m * N + n] = val;
        } else if (MODE == 1) {
          int b = m >> 11, s = m & (S_ - 1), hh = n >> 7, d = n & (HD - 1);
          ((u16*)Cout)[(((size_t)(b * Hh + hh)) * S_ + s) * HD + d] = f2bf(val);
        } else {
          int b = m >> 11, s = m & (S_ - 1), hh = n >> 7, d = n & (HD - 1);
          ((u16*)Cout)[(((size_t)(b * Hh + hh)) * HD + d) * S_ + s] = f2bf(val);
        }
      }
}

// ---------------- merged K+V projection (128^2 2-phase), blockIdx.z selects ----
// z=0: K proj -> RoPE -> Kr [b][kvh][s][128];  z=1: V proj -> Vt [b][kvh][d][s]
__global__ __launch_bounds__(256)
void gemm_kv(const u16* __restrict__ Xb, const u16* __restrict__ Wk,
             const u16* __restrict__ Wv, u16* __restrict__ Kr, u16* __restrict__ Vt,
             const float* __restrict__ fc, const float* __restrict__ fs) {
  const int tid = threadIdx.x;
  const int lid = tid & 63, w = tid >> 6;
  const int lr = lid & 15, lg = lid >> 4;
  const int wm = w >> 1, wn = w & 1;
  const int zz = blockIdx.z;
  const u16* Bw = zz ? Wv : Wk;
  const int K = D_, N = NKV * HD;

  const int gx = gridDim.x;
  const int nwg = gx * gridDim.y;
  const int lin = blockIdx.y * gx + blockIdx.x;
  const int cpx = nwg >> 3;
  const int lin2 = (lin & 7) * cpx + (lin >> 3);
  const int bm = (lin2 / gx) * 128, bn = (lin2 % gx) * 128;

  __shared__ __align__(16) u16 Al[128 * 64];
  __shared__ __align__(16) u16 Bl[128 * 64];
  f32x4 acc[4][4];
#pragma unroll
  for (int i = 0; i < 4; ++i)
#pragma unroll
    for (int j = 0; j < 4; ++j) acc[i][j] = (f32x4){0.f, 0.f, 0.f, 0.f};

  for (int k0 = 0; k0 < K; k0 += 64) {
    __syncthreads();
#pragma unroll
    for (int i = 0; i < 4; ++i) {
      int c = i * 256 + tid;
      int row = c >> 3, cb = c & 7;
      int cbs = (cb ^ row) & 7;
      load_lds16(Xb + (size_t)(bm + row) * K + k0 + cbs * 8, &Al[c * 8]);
    }
#pragma unroll
    for (int i = 0; i < 4; ++i) {
      int c = i * 256 + tid;
      int row = c >> 3, cb = c & 7;
      int cbs = (cb ^ row) & 7;
      load_lds16(Bw + (size_t)(bn + row) * K + k0 + cbs * 8, &Bl[c * 8]);
    }
    __syncthreads();
#pragma unroll
    for (int ks = 0; ks < 2; ++ks) {
      short8 af[4], bf[4];
#pragma unroll
      for (int mi = 0; mi < 4; ++mi) {
        int row = wm * 64 + mi * 16 + lr;
        af[mi] = *(const short8*)&Al[row * 64 + (((ks * 4 + lg) ^ row) & 7) * 8];
      }
#pragma unroll
      for (int ni = 0; ni < 4; ++ni) {
        int row = wn * 64 + ni * 16 + lr;
        bf[ni] = *(const short8*)&Bl[row * 64 + (((ks * 4 + lg) ^ row) & 7) * 8];
      }
#pragma unroll
      for (int mi = 0; mi < 4; ++mi)
#pragma unroll
        for (int ni = 0; ni < 4; ++ni)
          acc[mi][ni] = __builtin_amdgcn_mfma_f32_16x16x32_bf16(af[mi], bf[ni], acc[mi][ni], 0, 0, 0);
    }
  }
#pragma unroll
  for (int mi = 0; mi < 4; ++mi)
#pragma unroll
    for (int ni = 0; ni < 4; ++ni)
#pragma unroll
      for (int v = 0; v < 4; ++v) {
        int m = bm + wm * 64 + mi * 16 + lg * 4 + v;
        int n = bn + wn * 64 + ni * 16 + lr;
        float val = acc[mi][ni][v];
        int b = m >> 11, s = m & (S_ - 1), hh = n >> 7, d = n & (HD - 1);
        if (zz == 0) {
          int j = d >> 1;
          float c = fc[(size_t)s * 64 + j];
          float sn = fs[(size_t)s * 64 + j];
          float partner = __shfl_xor(val, 1);
          val = (n & 1) ? (val * c + partner * sn) : (val * c - partner * sn);
          Kr[(((size_t)(b * NKV + hh)) * S_ + s) * HD + d] = f2bf(val);
        } else {
          Vt[(((size_t)(b * NKV + hh)) * HD + d) * S_ + s] = f2bf(val);
        }
      }
}

// ---------------- Flash attention, swapped-QK form ----------------
__global__ __launch_bounds__(512, 4)
void attn_k(const u16* __restrict__ Qr, const u16* __restrict__ Kr,
            const u16* __restrict__ Vt, u16* __restrict__ Ao) {
  const int xp = blockIdx.x, h = blockIdx.y, b = blockIdx.z;
  const int kvh = h >> 2;
  const int tid = threadIdx.x, lid = tid & 63, w = tid >> 6;
  const int lr = lid & 15, lg = lid >> 4;
  __shared__ __align__(16) u16 Kl[2][64 * 128];
  __shared__ __align__(16) u16 Vl[2][128 * 64];
  __shared__ __align__(16) u32 Plw[8 * 512];

  const size_t qbase = ((size_t)(b * NH + h)) * S_ * HD;
  const size_t kbase = ((size_t)(b * NKV + kvh)) * S_ * HD;
  const size_t vbase = ((size_t)(b * NKV + kvh)) * HD * S_;
  const float scl = 0.08838834764831845f * 1.44269504088896340f;
  const int pb = w * 512 + lr * 32;
  const int qx = 4 * (lr & 7);

#define STAGE(BUF, KT)                                                              \
  do {                                                                              \
    _Pragma("unroll")                                                               \
    for (int i_ = 0; i_ < 2; ++i_) {                                                \
      int c_ = i_ * 512 + tid;                                                      \
      int row_ = c_ >> 4, cb_ = c_ & 15;                                            \
      int cbs_ = (cb_ & 8) | ((cb_ ^ row_) & 7);                                    \
      load_lds16(&Kr[kbase + (size_t)((KT) + row_) * HD + cbs_ * 8],                \
                 &Kl[BUF][(i_ * 512 + w * 64) * 8]);                                \
    }                                                                               \
    _Pragma("unroll")                                                               \
    for (int i_ = 0; i_ < 2; ++i_) {                                                \
      int c_ = i_ * 512 + tid;                                                      \
      int d_ = c_ >> 3, cb_ = c_ & 7;                                               \
      int cbs_ = (cb_ ^ d_) & 7;                                                    \
      load_lds16(&Vt[vbase + (size_t)d_ * S_ + (KT) + cbs_ * 8],                    \
                 &Vl[BUF][(i_ * 512 + w * 64) * 8]);                                \
    }                                                                               \
  } while (0)

  for (int part = 0; part < 2; ++part) {
    const int qi = part ? xp : (15 - xp);
    const int qb = qi * 128;
    const int ntiles = qi * 2 + 2;
    const int q_abs = qb + w * 16 + lr;

    short8 qf[4];
#pragma unroll
    for (int ks = 0; ks < 4; ++ks)
      qf[ks] = *(const short8*)&Qr[qbase + (size_t)q_abs * HD + ks * 32 + lg * 8];

    float m2 = -3.0e38f, osum = 0.f;
    f32x4 oacc[8];
#pragma unroll
    for (int nd = 0; nd < 8; ++nd) oacc[nd] = (f32x4){0.f, 0.f, 0.f, 0.f};

    STAGE(0, 0);
    __syncthreads();
    int cur = 0;

    for (int t = 0; t < ntiles; ++t) {
      const int kt = t * 64;
      if (t + 1 < ntiles) STAGE(cur ^ 1, kt + 64);

      f32x4 sc[4];
#pragma unroll
      for (int ni = 0; ni < 4; ++ni) sc[ni] = (f32x4){0.f, 0.f, 0.f, 0.f};
      __builtin_amdgcn_s_setprio(1);
#pragma unroll
      for (int ks = 0; ks < 4; ++ks) {
#pragma unroll
        for (int ni = 0; ni < 4; ++ni) {
          int row = ni * 16 + lr;
          int ch = ks * 4 + lg;
          int chs = (ch & 8) | ((ch ^ row) & 7);
          short8 kf = *(const short8*)&Kl[cur][row * 128 + chs * 8];
          sc[ni] = __builtin_amdgcn_mfma_f32_16x16x32_bf16(kf, qf[ks], sc[ni], 0, 0, 0);
        }
      }
      __builtin_amdgcn_s_setprio(0);

      const bool edge = (kt + 64 > qb);
      float mx = -3.0e38f;
#pragma unroll
      for (int ni = 0; ni < 4; ++ni)
#pragma unroll
        for (int v = 0; v < 4; ++v) {
          float s = sc[ni][v] * scl;
          int kv = kt + ni * 16 + lg * 4 + v;
          if (edge && kv > q_abs) s = -3.0e38f;
          sc[ni][v] = s;
          mx = fmaxf(mx, s);
        }
      mx = fmaxf(mx, __shfl_xor(mx, 16));
      mx = fmaxf(mx, __shfl_xor(mx, 32));

      if (__any(mx > m2 + 8.0f)) {
        float mnew = fmaxf(m2, mx);
        float fr = exp2f(m2 - mnew);
        m2 = mnew;
        osum *= fr;
#pragma unroll
        for (int nd = 0; nd < 8; ++nd) oacc[nd] *= fr;
      }

      float ps = 0.f;
#pragma unroll
      for (int ni = 0; ni < 4; ++ni) {
#pragma unroll
        for (int p = 0; p < 2; ++p) {
          float e0 = exp2f(sc[ni][2 * p] - m2);
          float e1 = exp2f(sc[ni][2 * p + 1] - m2);
          ps += e0 + e1;
          Plw[pb + ((8 * ni + 2 * lg + p) ^ qx)] = cvtpk_bf16(e0, e1);
        }
      }
      osum += ps;

      asm volatile("s_waitcnt lgkmcnt(0)" ::: "memory");
      __builtin_amdgcn_sched_barrier(0);

      __builtin_amdgcn_s_setprio(1);
#pragma unroll
      for (int ks = 0; ks < 2; ++ks) {
        short8 pfk = *(const short8*)&Plw[pb + ((16 * ks + 4 * lg) ^ qx)];
#pragma unroll
        for (int nd = 0; nd < 8; ++nd) {
          int rowv = nd * 16 + lr;
          int ch = ks * 4 + lg;
          short8 vf = *(const short8*)&Vl[cur][rowv * 64 + ((ch ^ rowv) & 7) * 8];
          oacc[nd] = __builtin_amdgcn_mfma_f32_16x16x32_bf16(vf, pfk, oacc[nd], 0, 0, 0);
        }
      }
      __builtin_amdgcn_s_setprio(0);
      __syncthreads();
      cur ^= 1;
    }

    float os = osum;
    os += __shfl_xor(os, 16);
    os += __shfl_xor(os, 32);
    const float inv = 1.0f / os;
    const size_t orow = ((size_t)(b * S_ + q_abs)) * D_ + h * HD;
    u32* AoW = (u32*)Ao;
#pragma unroll
    for (int nd = 0; nd < 8; ++nd) {
#pragma unroll
      for (int p = 0; p < 2; ++p) {
        u32 pk = cvtpk_bf16(oacc[nd][2 * p] * inv, oacc[nd][2 * p + 1] * inv);
        AoW[(orow + nd * 16 + lg * 4 + 2 * p) >> 1] = pk;
      }
    }
  }
#undef STAGE
}

// ---------------- host launch ----------------
extern "C" void kernel_launch(void* const* d_in, const int* in_sizes, int n_in,
                              void* d_out, int out_size, void* d_ws, size_t ws_size,
                              hipStream_t stream) {
  const float* x  = (const float*)d_in[0];
  const float* wq = (const float*)d_in[1];
  const float* wk = (const float*)d_in[2];
  const float* wv = (const float*)d_in[3];
  const float* wo = (const float*)d_in[4];
  const float* fc = (const float*)d_in[5];
  const float* fs = (const float*)d_in[6];

  const size_t SZ_X  = (size_t)B_ * S_ * D_ * 2;
  const size_t SZ_WQ = (size_t)D_ * D_ * 2;
  const size_t SZ_WK = (size_t)NKV * HD * D_ * 2;
  char* ws = (char*)d_ws;
  u16* Xb  = (u16*)(ws);
  u16* Wqb = (u16*)(ws + SZ_X);
  u16* Wkb = (u16*)(ws + SZ_X + SZ_WQ);
  u16* Wvb = (u16*)(ws + SZ_X + SZ_WQ + SZ_WK);
  u16* Wob = (u16*)(ws + SZ_X + SZ_WQ + 2 * SZ_WK);
  u16* Qr  = (u16*)(ws + SZ_X + 2 * SZ_WQ + 2 * SZ_WK);
  u16* Kr  = (u16*)(ws + 2 * SZ_X + 2 * SZ_WQ + 2 * SZ_WK);
  u16* Vt  = (u16*)(ws + 2 * SZ_X + 2 * SZ_WQ + 3 * SZ_WK);
  u16* Ao  = (u16*)(ws + 2 * SZ_X + 2 * SZ_WQ + 4 * SZ_WK);
  const size_t NEEDED = 3 * SZ_X + 2 * SZ_WQ + 4 * SZ_WK;
  if (ws_size < NEEDED) return;

  // all fp32->bf16 conversions in one dispatch (7,340,032 chunks / 256)
  cvt_all<<<28672, 256, 0, stream>>>(x, wq, wk, wv, wo, Xb, Wqb, Wkb, Wvb, Wob);

  // Q projection (4096x4096x4096), deep-pipelined 256^2, fused RoPE
  gemm256<1, true><<<dim3(16, 16), 512, 0, stream>>>(
      Xb, Wqb, Qr, B_ * S_, D_, D_, NH, fc, fs);
  // K+V projections merged (z selects), 128^2 kernel
  gemm_kv<<<dim3(8, 32, 2), 256, 0, stream>>>(Xb, Wkb, Wvb, Kr, Vt, fc, fs);

  attn_k<<<dim3(8, NH, B_), 512, 0, stream>>>(Qr, Kr, Vt, Ao);

  // O projection (4096x4096x4096), fp32 output
  gemm256<0, false><<<dim3(16, 16), 512, 0, stream>>>(
      Ao, Wob, d_out, B_ * S_, D_, D_, 0, nullptr, nullptr);
}

// Round 7
// 507.823 us; speedup vs baseline: 2.2897x; 1.0295x over previous
//
#include <hip/hip_runtime.h>
#include <cstdint>
#include <cstddef>

#define B_  2
#define S_  2048
#define D_  4096
#define NH  32
#define NKV 8
#define HD  128

typedef unsigned short u16;
typedef unsigned int   u32;
typedef __attribute__((ext_vector_type(8))) short short8;
typedef __attribute__((ext_vector_type(4))) float f32x4;
typedef __attribute__((ext_vector_type(4))) u32   u32x4;

__device__ __forceinline__ u16 f2bf(float f) {
  u32 u = __float_as_uint(f);
  u32 r = (u + 0x7FFFu + ((u >> 16) & 1u)) >> 16;  // RNE
  return (u16)r;
}
__device__ __forceinline__ float bf2f(u32 lo16) {
  return __uint_as_float(lo16 << 16);
}
__device__ __forceinline__ u32 cvtpk_bf16(float lo, float hi) {
  u32 r;
  asm("v_cvt_pk_bf16_f32 %0, %1, %2" : "=v"(r) : "v"(lo), "v"(hi));
  return r;
}
__device__ __forceinline__ short8 u32x4_to_short8(u32x4 v) {
  union { u32x4 a; short8 b; } u; u.a = v; return u.b;
}
__device__ __forceinline__ void load_lds16(const void* g, void* lds) {
  __builtin_amdgcn_global_load_lds(
      (const __attribute__((address_space(1))) u32*)g,
      (__attribute__((address_space(3))) u32*)lds, 16, 0, 0);
}

// ---------------- fused fp32 -> bf16 converter for all 5 tensors ----------------
__global__ __launch_bounds__(256) void cvt_all(
    const float* __restrict__ x, const float* __restrict__ wq,
    const float* __restrict__ wk, const float* __restrict__ wv,
    const float* __restrict__ wo, u16* __restrict__ Xb, u16* __restrict__ Wqb,
    u16* __restrict__ Wkb, u16* __restrict__ Wvb, u16* __restrict__ Wob) {
  long i = (long)blockIdx.x * 256 + threadIdx.x;
  const float* src; u16* dst; long off;
  if (i < 2097152L)      { src = x;  dst = Xb;  off = i; }
  else if (i < 4194304L) { src = wq; dst = Wqb; off = i - 2097152L; }
  else if (i < 4718592L) { src = wk; dst = Wkb; off = i - 4194304L; }
  else if (i < 5242880L) { src = wv; dst = Wvb; off = i - 4718592L; }
  else                   { src = wo; dst = Wob; off = i - 5242880L; }
  const float4* s = (const float4*)src + off * 2;
  float4 a = s[0], b = s[1];
  uint4 o;
  o.x = (u32)f2bf(a.x) | ((u32)f2bf(a.y) << 16);
  o.y = (u32)f2bf(a.z) | ((u32)f2bf(a.w) << 16);
  o.z = (u32)f2bf(b.x) | ((u32)f2bf(b.y) << 16);
  o.w = (u32)f2bf(b.z) | ((u32)f2bf(b.w) << 16);
  *((uint4*)dst + off) = o;
}

// ================= 256^2 tile, 4-phase/K-tile counted-vmcnt GEMM =================
// ROPE epilogue also folds the attention scale (log2e/sqrt(HD)) into Q.
template <int MODE, bool ROPE>
__global__ __launch_bounds__(512, 2)
void gemm256(const u16* __restrict__ A, const u16* __restrict__ Bw,
             void* __restrict__ Cout, int M, int N, int K, int Hh,
             const float* __restrict__ fc, const float* __restrict__ fs) {
  const int tid = threadIdx.x, lid = tid & 63, w = tid >> 6;
  const int lr = lid & 15, lg = lid >> 4;
  const int wm = w >> 2, wn = w & 3;

  int lin = blockIdx.y * gridDim.x + blockIdx.x;
  int bm, bn;
  if (gridDim.x == 16 && gridDim.y == 16) {
    int xcd = lin & 7, idx = lin >> 3;
    bm = ((xcd & 3) * 4 + (idx >> 3)) * 256;
    bn = ((xcd >> 2) * 8 + (idx & 7)) * 256;
  } else {
    bm = blockIdx.y * 256;
    bn = blockIdx.x * 256;
  }

  __shared__ __align__(16) u16 Al[2][2][8192];  // [buf][khalf][row*32 + slot*8]
  __shared__ __align__(16) u16 Bl[2][2][8192];

  f32x4 acc[8][4];
#pragma unroll
  for (int i = 0; i < 8; ++i)
#pragma unroll
    for (int j = 0; j < 4; ++j) acc[i][j] = (f32x4){0.f, 0.f, 0.f, 0.f};

#define STG_A(B2, KS, K0)                                                       \
  do {                                                                          \
    _Pragma("unroll")                                                           \
    for (int j_ = 0; j_ < 2; ++j_) {                                            \
      int c_ = j_ * 512 + tid;                                                  \
      int r_ = c_ >> 2, cb_ = c_ & 3;                                           \
      int s_ = (cb_ ^ (r_ >> 1)) & 3;                                           \
      load_lds16(A + (size_t)(bm + r_) * K + (K0) + (KS) * 32 + s_ * 8,         \
                 &Al[B2][KS][c_ * 8]);                                          \
    }                                                                           \
  } while (0)
#define STG_B(B2, KS, K0)                                                       \
  do {                                                                          \
    _Pragma("unroll")                                                           \
    for (int j_ = 0; j_ < 2; ++j_) {                                            \
      int c_ = j_ * 512 + tid;                                                  \
      int r_ = c_ >> 2, cb_ = c_ & 3;                                           \
      int s_ = (cb_ ^ (r_ >> 1)) & 3;                                           \
      load_lds16(Bw + (size_t)(bn + r_) * K + (K0) + (KS) * 32 + s_ * 8,        \
                 &Bl[B2][KS][c_ * 8]);                                          \
    }                                                                           \
  } while (0)

  const int nt = K >> 6;
  STG_A(0, 0, 0); STG_B(0, 0, 0); STG_A(0, 1, 0); STG_B(0, 1, 0);
  STG_A(1, 0, 64); STG_B(1, 0, 64);
  asm volatile("s_waitcnt vmcnt(8)" ::: "memory");
  __builtin_amdgcn_s_barrier();

  for (int t = 0; t < nt; ++t) {
    const int buf = t & 1, bufN = buf ^ 1;
    const int k1 = (t + 1) << 6, k2 = (t + 2) << 6;
    const bool pf1 = (t + 1 < nt), pf2 = (t + 2 < nt);
    short8 a[4], bfr[4];

#pragma unroll
    for (int ni = 0; ni < 4; ++ni) {
      int r = wn * 64 + ni * 16 + lr;
      bfr[ni] = *(const short8*)&Bl[buf][0][r * 32 + ((lg ^ (r >> 1)) & 3) * 8];
    }
#pragma unroll
    for (int mi = 0; mi < 4; ++mi) {
      int r = wm * 128 + mi * 16 + lr;
      a[mi] = *(const short8*)&Al[buf][0][r * 32 + ((lg ^ (r >> 1)) & 3) * 8];
    }
    if (pf1) STG_A(bufN, 1, k1);
    __builtin_amdgcn_s_barrier();
    __builtin_amdgcn_s_setprio(1);
#pragma unroll
    for (int mi = 0; mi < 4; ++mi)
#pragma unroll
      for (int ni = 0; ni < 4; ++ni)
        acc[mi][ni] = __builtin_amdgcn_mfma_f32_16x16x32_bf16(a[mi], bfr[ni], acc[mi][ni], 0, 0, 0);
    __builtin_amdgcn_s_setprio(0);

#pragma unroll
    for (int mi = 0; mi < 4; ++mi) {
      int r = wm * 128 + (mi + 4) * 16 + lr;
      a[mi] = *(const short8*)&Al[buf][0][r * 32 + ((lg ^ (r >> 1)) & 3) * 8];
    }
    if (pf1) STG_B(bufN, 1, k1);
    __builtin_amdgcn_s_barrier();
    __builtin_amdgcn_s_setprio(1);
#pragma unroll
    for (int mi = 0; mi < 4; ++mi)
#pragma unroll
      for (int ni = 0; ni < 4; ++ni)
        acc[mi + 4][ni] = __builtin_amdgcn_mfma_f32_16x16x32_bf16(a[mi], bfr[ni], acc[mi + 4][ni], 0, 0, 0);
    __builtin_amdgcn_s_setprio(0);

    if (pf1) asm volatile("s_waitcnt vmcnt(8)" ::: "memory");
    else     asm volatile("s_waitcnt vmcnt(0)" ::: "memory");
    __builtin_amdgcn_s_barrier();

#pragma unroll
    for (int ni = 0; ni < 4; ++ni) {
      int r = wn * 64 + ni * 16 + lr;
      bfr[ni] = *(const short8*)&Bl[buf][1][r * 32 + ((lg ^ (r >> 1)) & 3) * 8];
    }
#pragma unroll
    for (int mi = 0; mi < 4; ++mi) {
      int r = wm * 128 + mi * 16 + lr;
      a[mi] = *(const short8*)&Al[buf][1][r * 32 + ((lg ^ (r >> 1)) & 3) * 8];
    }
    if (pf2) STG_A(buf, 0, k2);
    __builtin_amdgcn_s_barrier();
    __builtin_amdgcn_s_setprio(1);
#pragma unroll
    for (int mi = 0; mi < 4; ++mi)
#pragma unroll
      for (int ni = 0; ni < 4; ++ni)
        acc[mi][ni] = __builtin_amdgcn_mfma_f32_16x16x32_bf16(a[mi], bfr[ni], acc[mi][ni], 0, 0, 0);
    __builtin_amdgcn_s_setprio(0);

#pragma unroll
    for (int mi = 0; mi < 4; ++mi) {
      int r = wm * 128 + (mi + 4) * 16 + lr;
      a[mi] = *(const short8*)&Al[buf][1][r * 32 + ((lg ^ (r >> 1)) & 3) * 8];
    }
    if (pf2) STG_B(buf, 0, k2);
    __builtin_amdgcn_s_barrier();
    __builtin_amdgcn_s_setprio(1);
#pragma unroll
    for (int mi = 0; mi < 4; ++mi)
#pragma unroll
      for (int ni = 0; ni < 4; ++ni)
        acc[mi + 4][ni] = __builtin_amdgcn_mfma_f32_16x16x32_bf16(a[mi], bfr[ni], acc[mi + 4][ni], 0, 0, 0);
    __builtin_amdgcn_s_setprio(0);

    if (pf1) {
      if (pf2) asm volatile("s_waitcnt vmcnt(8)" ::: "memory");
      else     asm volatile("s_waitcnt vmcnt(4)" ::: "memory");
      __builtin_amdgcn_s_barrier();
    }
  }
#undef STG_A
#undef STG_B

#pragma unroll
  for (int mi = 0; mi < 8; ++mi)
#pragma unroll
    for (int ni = 0; ni < 4; ++ni)
#pragma unroll
      for (int v = 0; v < 4; ++v) {
        int m = bm + wm * 128 + mi * 16 + lg * 4 + v;
        int n = bn + wn * 64 + ni * 16 + lr;
        float val = acc[mi][ni][v];
        if (ROPE) {
          int srow = m & (S_ - 1);
          int j = (n & (HD - 1)) >> 1;
          float c = fc[(size_t)srow * 64 + j];
          float s = fs[(size_t)srow * 64 + j];
          float partner = __shfl_xor(val, 1);
          val = (n & 1) ? (val * c + partner * s) : (val * c - partner * s);
          val *= (0.08838834764831845f * 1.44269504088896340f);  // fold attn scale (log2 domain) into Q
        }
        if (MODE == 0) {
          ((float*)Cout)[(size_t)m * N + n] = val;
        } else if (MODE == 1) {
          int b = m >> 11, s = m & (S_ - 1), hh = n >> 7, d = n & (HD - 1);
          ((u16*)Cout)[(((size_t)(b * Hh + hh)) * S_ + s) * HD + d] = f2bf(val);
        } else {
          int b = m >> 11, s = m & (S_ - 1), hh = n >> 7, d = n & (HD - 1);
          ((u16*)Cout)[(((size_t)(b * Hh + hh)) * HD + d) * S_ + s] = f2bf(val);
        }
      }
}

// ---------------- merged K+V projection (128^2 2-phase), blockIdx.z selects ----
// z=0: K proj -> RoPE -> Kr.  z=1: V proj -> Vt [b][kvh][d][s'] with per-32
// s-permutation p(x)=8*((x>>2)&3)+4*((x>>4)&1)+(x&3) so attention's PV A-operand
// k-slots line up with P's in-lane layout (zero-shuffle PV).
__global__ __launch_bounds__(256)
void gemm_kv(const u16* __restrict__ Xb, const u16* __restrict__ Wk,
             const u16* __restrict__ Wv, u16* __restrict__ Kr, u16* __restrict__ Vt,
             const float* __restrict__ fc, const float* __restrict__ fs) {
  const int tid = threadIdx.x;
  const int lid = tid & 63, w = tid >> 6;
  const int lr = lid & 15, lg = lid >> 4;
  const int wm = w >> 1, wn = w & 1;
  const int zz = blockIdx.z;
  const u16* Bw = zz ? Wv : Wk;
  const int K = D_;

  const int gx = gridDim.x;
  const int nwg = gx * gridDim.y;
  const int lin = blockIdx.y * gx + blockIdx.x;
  const int cpx = nwg >> 3;
  const int lin2 = (lin & 7) * cpx + (lin >> 3);
  const int bm = (lin2 / gx) * 128, bn = (lin2 % gx) * 128;

  __shared__ __align__(16) u16 Al[128 * 64];
  __shared__ __align__(16) u16 Bl[128 * 64];
  f32x4 acc[4][4];
#pragma unroll
  for (int i = 0; i < 4; ++i)
#pragma unroll
    for (int j = 0; j < 4; ++j) acc[i][j] = (f32x4){0.f, 0.f, 0.f, 0.f};

  for (int k0 = 0; k0 < K; k0 += 64) {
    __syncthreads();
#pragma unroll
    for (int i = 0; i < 4; ++i) {
      int c = i * 256 + tid;
      int row = c >> 3, cb = c & 7;
      int cbs = (cb ^ row) & 7;
      load_lds16(Xb + (size_t)(bm + row) * K + k0 + cbs * 8, &Al[c * 8]);
    }
#pragma unroll
    for (int i = 0; i < 4; ++i) {
      int c = i * 256 + tid;
      int row = c >> 3, cb = c & 7;
      int cbs = (cb ^ row) & 7;
      load_lds16(Bw + (size_t)(bn + row) * K + k0 + cbs * 8, &Bl[c * 8]);
    }
    __syncthreads();
#pragma unroll
    for (int ks = 0; ks < 2; ++ks) {
      short8 af[4], bf[4];
#pragma unroll
      for (int mi = 0; mi < 4; ++mi) {
        int row = wm * 64 + mi * 16 + lr;
        af[mi] = *(const short8*)&Al[row * 64 + (((ks * 4 + lg) ^ row) & 7) * 8];
      }
#pragma unroll
      for (int ni = 0; ni < 4; ++ni) {
        int row = wn * 64 + ni * 16 + lr;
        bf[ni] = *(const short8*)&Bl[row * 64 + (((ks * 4 + lg) ^ row) & 7) * 8];
      }
#pragma unroll
      for (int mi = 0; mi < 4; ++mi)
#pragma unroll
        for (int ni = 0; ni < 4; ++ni)
          acc[mi][ni] = __builtin_amdgcn_mfma_f32_16x16x32_bf16(af[mi], bf[ni], acc[mi][ni], 0, 0, 0);
    }
  }
#pragma unroll
  for (int mi = 0; mi < 4; ++mi)
#pragma unroll
    for (int ni = 0; ni < 4; ++ni)
#pragma unroll
      for (int v = 0; v < 4; ++v) {
        int m = bm + wm * 64 + mi * 16 + lg * 4 + v;
        int n = bn + wn * 64 + ni * 16 + lr;
        float val = acc[mi][ni][v];
        int b = m >> 11, s = m & (S_ - 1), hh = n >> 7, d = n & (HD - 1);
        if (zz == 0) {
          int j = d >> 1;
          float c = fc[(size_t)s * 64 + j];
          float sn = fs[(size_t)s * 64 + j];
          float partner = __shfl_xor(val, 1);
          val = (n & 1) ? (val * c + partner * sn) : (val * c - partner * sn);
          Kr[(((size_t)(b * NKV + hh)) * S_ + s) * HD + d] = f2bf(val);
        } else {
          int x = s & 31;
          int sp = (s & ~31) | (((x >> 2) & 3) * 8 + ((x >> 4) & 1) * 4 + (x & 3));
          Vt[(((size_t)(b * NKV + hh)) * HD + d) * S_ + sp] = f2bf(val);
        }
      }
}

// ---------------- Flash attention, swapped-QK + zero-shuffle PV ----------------
// Grid (8, NH, B), 512 threads (8 waves x 16 q-rows). Q pre-scaled (log2 domain).
// After QK^T, lane (lr,lg) holds P[kv=16ni+4lg+v][q=lr]; cvtpk packs these into
// 8 u32 words that ARE the PV B-operand fragments (k-slot sigma(lg,j) =
// 16*(j>>2)+4lg+(j&3)); V was stored s-permuted to match. No P LDS roundtrip.
__global__ __launch_bounds__(512, 4)
void attn_k(const u16* __restrict__ Qr, const u16* __restrict__ Kr,
            const u16* __restrict__ Vt, u16* __restrict__ Ao) {
  const int xp = blockIdx.x, h = blockIdx.y, b = blockIdx.z;
  const int kvh = h >> 2;
  const int tid = threadIdx.x, lid = tid & 63, w = tid >> 6;
  const int lr = lid & 15, lg = lid >> 4;
  __shared__ __align__(16) u16 Kl[2][64 * 128];
  __shared__ __align__(16) u16 Vl[2][128 * 64];

  const size_t qbase = ((size_t)(b * NH + h)) * S_ * HD;
  const size_t kbase = ((size_t)(b * NKV + kvh)) * S_ * HD;
  const size_t vbase = ((size_t)(b * NKV + kvh)) * HD * S_;

#define STAGE(BUF, KT)                                                              \
  do {                                                                              \
    _Pragma("unroll")                                                               \
    for (int i_ = 0; i_ < 2; ++i_) {                                                \
      int c_ = i_ * 512 + tid;                                                      \
      int row_ = c_ >> 4, cb_ = c_ & 15;                                            \
      int cbs_ = (cb_ & 8) | ((cb_ ^ row_) & 7);                                    \
      load_lds16(&Kr[kbase + (size_t)((KT) + row_) * HD + cbs_ * 8],                \
                 &Kl[BUF][(i_ * 512 + w * 64) * 8]);                                \
    }                                                                               \
    _Pragma("unroll")                                                               \
    for (int i_ = 0; i_ < 2; ++i_) {                                                \
      int c_ = i_ * 512 + tid;                                                      \
      int d_ = c_ >> 3, cb_ = c_ & 7;                                               \
      int cbs_ = (cb_ ^ d_) & 7;                                                    \
      load_lds16(&Vt[vbase + (size_t)d_ * S_ + (KT) + cbs_ * 8],                    \
                 &Vl[BUF][(i_ * 512 + w * 64) * 8]);                                \
    }                                                                               \
  } while (0)

  for (int part = 0; part < 2; ++part) {
    const int qi = part ? xp : (15 - xp);
    const int qb = qi * 128;
    const int ntiles = qi * 2 + 2;
    const int q_abs = qb + w * 16 + lr;

    short8 qf[4];
#pragma unroll
    for (int ks = 0; ks < 4; ++ks)
      qf[ks] = *(const short8*)&Qr[qbase + (size_t)q_abs * HD + ks * 32 + lg * 8];

    float m2 = -3.0e38f, osum = 0.f;
    f32x4 oacc[8];
#pragma unroll
    for (int nd = 0; nd < 8; ++nd) oacc[nd] = (f32x4){0.f, 0.f, 0.f, 0.f};

    STAGE(0, 0);
    __syncthreads();
    int cur = 0;

    for (int t = 0; t < ntiles; ++t) {
      const int kt = t * 64;
      if (t + 1 < ntiles) STAGE(cur ^ 1, kt + 64);

      // ---- sc[ni] = K Q^T (already log2-scaled via Q)
      f32x4 sc[4];
#pragma unroll
      for (int ni = 0; ni < 4; ++ni) sc[ni] = (f32x4){0.f, 0.f, 0.f, 0.f};
      __builtin_amdgcn_s_setprio(1);
#pragma unroll
      for (int ks = 0; ks < 4; ++ks) {
#pragma unroll
        for (int ni = 0; ni < 4; ++ni) {
          int row = ni * 16 + lr;
          int ch = ks * 4 + lg;
          int chs = (ch & 8) | ((ch ^ row) & 7);
          short8 kf = *(const short8*)&Kl[cur][row * 128 + chs * 8];
          sc[ni] = __builtin_amdgcn_mfma_f32_16x16x32_bf16(kf, qf[ks], sc[ni], 0, 0, 0);
        }
      }
      __builtin_amdgcn_s_setprio(0);

      // ---- causal mask (edge tiles only), in-lane tree max
      const bool edge = (kt + 64 > qb);
      if (edge) {
#pragma unroll
        for (int ni = 0; ni < 4; ++ni)
#pragma unroll
          for (int v = 0; v < 4; ++v) {
            int kv = kt + ni * 16 + lg * 4 + v;
            if (kv > q_abs) sc[ni][v] = -3.0e38f;
          }
      }
      float mab = fmaxf(fmaxf(fmaxf(sc[0][0], sc[0][1]), fmaxf(sc[0][2], sc[0][3])),
                        fmaxf(fmaxf(sc[1][0], sc[1][1]), fmaxf(sc[1][2], sc[1][3])));
      float mcd = fmaxf(fmaxf(fmaxf(sc[2][0], sc[2][1]), fmaxf(sc[2][2], sc[2][3])),
                        fmaxf(fmaxf(sc[3][0], sc[3][1]), fmaxf(sc[3][2], sc[3][3])));
      float mx = fmaxf(mab, mcd);
      mx = fmaxf(mx, __shfl_xor(mx, 16));
      mx = fmaxf(mx, __shfl_xor(mx, 32));

      // ---- defer-max rescale (skip when growth <= 8 in log2 units)
      if (__any(mx > m2 + 8.0f)) {
        float mnew = fmaxf(m2, mx);
        float fr = exp2f(m2 - mnew);
        m2 = mnew;
        osum *= fr;
#pragma unroll
        for (int nd = 0; nd < 8; ++nd) oacc[nd] *= fr;
      }

      // ---- P = exp2(s - m): pack straight into PV B-operand fragments
      u32x4 pw0, pw1;
      float ps = 0.f;
#pragma unroll
      for (int ni = 0; ni < 4; ++ni) {
#pragma unroll
        for (int p = 0; p < 2; ++p) {
          float e0 = exp2f(sc[ni][2 * p] - m2);
          float e1 = exp2f(sc[ni][2 * p + 1] - m2);
          ps += e0 + e1;
          u32 pk = cvtpk_bf16(e0, e1);
          if (ni < 2) pw0[(ni & 1) * 2 + p] = pk;
          else        pw1[(ni & 1) * 2 + p] = pk;
        }
      }
      osum += ps;
      const short8 pf0 = u32x4_to_short8(pw0);
      const short8 pf1 = u32x4_to_short8(pw1);

      // ---- O^T += V^T P^T : P fragments direct from registers
      __builtin_amdgcn_s_setprio(1);
#pragma unroll
      for (int ks = 0; ks < 2; ++ks) {
        const short8 pfk = ks ? pf1 : pf0;
#pragma unroll
        for (int nd = 0; nd < 8; ++nd) {
          int rowv = nd * 16 + lr;
          int ch = ks * 4 + lg;
          short8 vf = *(const short8*)&Vl[cur][rowv * 64 + ((ch ^ rowv) & 7) * 8];
          oacc[nd] = __builtin_amdgcn_mfma_f32_16x16x32_bf16(vf, pfk, oacc[nd], 0, 0, 0);
        }
      }
      __builtin_amdgcn_s_setprio(0);
      __syncthreads();
      cur ^= 1;
    }

    float os = osum;
    os += __shfl_xor(os, 16);
    os += __shfl_xor(os, 32);
    const float inv = 1.0f / os;
    const size_t orow = ((size_t)(b * S_ + q_abs)) * D_ + h * HD;
    u32* AoW = (u32*)Ao;
#pragma unroll
    for (int nd = 0; nd < 8; ++nd) {
#pragma unroll
      for (int p = 0; p < 2; ++p) {
        u32 pk = cvtpk_bf16(oacc[nd][2 * p] * inv, oacc[nd][2 * p + 1] * inv);
        AoW[(orow + nd * 16 + lg * 4 + 2 * p) >> 1] = pk;
      }
    }
  }
#undef STAGE
}

// ---------------- host launch ----------------
extern "C" void kernel_launch(void* const* d_in, const int* in_sizes, int n_in,
                              void* d_out, int out_size, void* d_ws, size_t ws_size,
                              hipStream_t stream) {
  const float* x  = (const float*)d_in[0];
  const float* wq = (const float*)d_in[1];
  const float* wk = (const float*)d_in[2];
  const float* wv = (const float*)d_in[3];
  const float* wo = (const float*)d_in[4];
  const float* fc = (const float*)d_in[5];
  const float* fs = (const float*)d_in[6];

  const size_t SZ_X  = (size_t)B_ * S_ * D_ * 2;
  const size_t SZ_WQ = (size_t)D_ * D_ * 2;
  const size_t SZ_WK = (size_t)NKV * HD * D_ * 2;
  char* ws = (char*)d_ws;
  u16* Xb  = (u16*)(ws);
  u16* Wqb = (u16*)(ws + SZ_X);
  u16* Wkb = (u16*)(ws + SZ_X + SZ_WQ);
  u16* Wvb = (u16*)(ws + SZ_X + SZ_WQ + SZ_WK);
  u16* Wob = (u16*)(ws + SZ_X + SZ_WQ + 2 * SZ_WK);
  u16* Qr  = (u16*)(ws + SZ_X + 2 * SZ_WQ + 2 * SZ_WK);
  u16* Kr  = (u16*)(ws + 2 * SZ_X + 2 * SZ_WQ + 2 * SZ_WK);
  u16* Vt  = (u16*)(ws + 2 * SZ_X + 2 * SZ_WQ + 3 * SZ_WK);
  u16* Ao  = (u16*)(ws + 2 * SZ_X + 2 * SZ_WQ + 4 * SZ_WK);
  const size_t NEEDED = 3 * SZ_X + 2 * SZ_WQ + 4 * SZ_WK;
  if (ws_size < NEEDED) return;

  cvt_all<<<28672, 256, 0, stream>>>(x, wq, wk, wv, wo, Xb, Wqb, Wkb, Wvb, Wob);

  gemm256<1, true><<<dim3(16, 16), 512, 0, stream>>>(
      Xb, Wqb, Qr, B_ * S_, D_, D_, NH, fc, fs);
  gemm_kv<<<dim3(8, 32, 2), 256, 0, stream>>>(Xb, Wkb, Wvb, Kr, Vt, fc, fs);

  attn_k<<<dim3(8, NH, B_), 512, 0, stream>>>(Qr, Kr, Vt, Ao);

  gemm256<0, false><<<dim3(16, 16), 512, 0, stream>>>(
      Ao, Wob, d_out, B_ * S_, D_, D_, 0, nullptr, nullptr);
}

// Round 8
// 500.720 us; speedup vs baseline: 2.3222x; 1.0142x over previous
//
#include <hip/hip_runtime.h>
#include <cstdint>
#include <cstddef>

#define B_  2
#define S_  2048
#define D_  4096
#define NH  32
#define NKV 8
#define HD  128

typedef unsigned short u16;
typedef unsigned int   u32;
typedef __attribute__((ext_vector_type(8))) short short8;
typedef __attribute__((ext_vector_type(4))) float f32x4;
typedef __attribute__((ext_vector_type(4))) u32   u32x4;

__device__ __forceinline__ u16 f2bf(float f) {
  u32 u = __float_as_uint(f);
  u32 r = (u + 0x7FFFu + ((u >> 16) & 1u)) >> 16;  // RNE
  return (u16)r;
}
__device__ __forceinline__ float bf2f(u32 lo16) {
  return __uint_as_float(lo16 << 16);
}
__device__ __forceinline__ u32 cvtpk_bf16(float lo, float hi) {
  u32 r;
  asm("v_cvt_pk_bf16_f32 %0, %1, %2" : "=v"(r) : "v"(lo), "v"(hi));
  return r;
}
__device__ __forceinline__ short8 u32x4_to_short8(u32x4 v) {
  union { u32x4 a; short8 b; } u; u.a = v; return u.b;
}
__device__ __forceinline__ void load_lds16(const void* g, void* lds) {
  __builtin_amdgcn_global_load_lds(
      (const __attribute__((address_space(1))) u32*)g,
      (__attribute__((address_space(3))) u32*)lds, 16, 0, 0);
}

// ---------------- fused fp32 -> bf16 converter for all 5 tensors ----------------
__global__ __launch_bounds__(256) void cvt_all(
    const float* __restrict__ x, const float* __restrict__ wq,
    const float* __restrict__ wk, const float* __restrict__ wv,
    const float* __restrict__ wo, u16* __restrict__ Xb, u16* __restrict__ Wqb,
    u16* __restrict__ Wkb, u16* __restrict__ Wvb, u16* __restrict__ Wob) {
  long i = (long)blockIdx.x * 256 + threadIdx.x;
  const float* src; u16* dst; long off;
  if (i < 2097152L)      { src = x;  dst = Xb;  off = i; }
  else if (i < 4194304L) { src = wq; dst = Wqb; off = i - 2097152L; }
  else if (i < 4718592L) { src = wk; dst = Wkb; off = i - 4194304L; }
  else if (i < 5242880L) { src = wv; dst = Wvb; off = i - 4718592L; }
  else                   { src = wo; dst = Wob; off = i - 5242880L; }
  const float4* s = (const float4*)src + off * 2;
  float4 a = s[0], b = s[1];
  uint4 o;
  o.x = (u32)f2bf(a.x) | ((u32)f2bf(a.y) << 16);
  o.y = (u32)f2bf(a.z) | ((u32)f2bf(a.w) << 16);
  o.z = (u32)f2bf(b.x) | ((u32)f2bf(b.y) << 16);
  o.w = (u32)f2bf(b.z) | ((u32)f2bf(b.w) << 16);
  *((uint4*)dst + off) = o;
}

// ================= 256^2 tile, 8-phase / 2-K-tile counted-vmcnt GEMM =============
// m201-style schedule. 512 thr = 8 waves (2M x 4N), wave tile 128x64.
// LDS per matrix: [2 buf][2 region][128 rows][64 k] (A regions = m-quadrant halves,
// B regions = n-halves). Per phase: ds_read subtile + stage 1 half-tile (2 loads)
// -> s_barrier -> 16 MFMA (setprio) -> s_barrier. vmcnt(6) ONLY at phases 4 & 8.
// Buffers: tile t lives in buf = t&1. Regions freed phase-by-phase, restaged for
// tile t+2 with 3..6 phases of slack. Steady state: 8 loads outstanding at each
// wait; vmcnt(6) guarantees all but the newest 3 half-tiles landed.
template <int MODE, bool ROPE>
__global__ __launch_bounds__(512, 2)
void gemm256(const u16* __restrict__ A, const u16* __restrict__ Bw,
             void* __restrict__ Cout, int M, int N, int K, int Hh,
             const float* __restrict__ fc, const float* __restrict__ fs) {
  const int tid = threadIdx.x, lid = tid & 63, w = tid >> 6;
  const int lr = lid & 15, lg = lid >> 4;
  const int wm = w >> 2, wn = w & 3;

  // chunked XCD swizzle for the 16x16 grid
  int lin = blockIdx.y * gridDim.x + blockIdx.x;
  int bm, bn;
  if (gridDim.x == 16 && gridDim.y == 16) {
    int xcd = lin & 7, idx = lin >> 3;
    bm = ((xcd & 3) * 4 + (idx >> 3)) * 256;
    bn = ((xcd >> 2) * 8 + (idx & 7)) * 256;
  } else {
    bm = blockIdx.y * 256;
    bn = blockIdx.x * 256;
  }

  // A region mh: rows r with ((r>>6)&1)==mh, local idx = ((r&128)>>1)|(r&63)
  // B region nh: rows r with ((r>>5)&1)==nh, local idx = ((r&192)>>1)|(r&31)
  __shared__ __align__(16) u16 Al[2][2][128 * 64];
  __shared__ __align__(16) u16 Bl[2][2][128 * 64];

  f32x4 acc[8][4];
#pragma unroll
  for (int i = 0; i < 8; ++i)
#pragma unroll
    for (int j = 0; j < 4; ++j) acc[i][j] = (f32x4){0.f, 0.f, 0.f, 0.f};

#define STG_AQ(BUF, QH, KT)                                                    \
  do {                                                                         \
    _Pragma("unroll")                                                          \
    for (int j_ = 0; j_ < 2; ++j_) {                                           \
      int c_ = j_ * 512 + tid;                                                 \
      int idx_ = c_ >> 3, cb_ = c_ & 7;                                        \
      int sr_ = bm + ((idx_ & 64) << 1) + (QH) * 64 + (idx_ & 63);             \
      int sc_ = (cb_ ^ idx_) & 7;                                              \
      load_lds16(A + (size_t)sr_ * K + (KT) + sc_ * 8, &Al[BUF][QH][c_ * 8]);  \
    }                                                                          \
  } while (0)
#define STG_BN(BUF, NHh, KT)                                                   \
  do {                                                                         \
    _Pragma("unroll")                                                          \
    for (int j_ = 0; j_ < 2; ++j_) {                                           \
      int c_ = j_ * 512 + tid;                                                 \
      int idx_ = c_ >> 3, cb_ = c_ & 7;                                        \
      int sr_ = bn + ((idx_ & 96) << 1) + (NHh) * 32 + (idx_ & 31);            \
      int sc_ = (cb_ ^ idx_) & 7;                                              \
      load_lds16(Bw + (size_t)sr_ * K + (KT) + sc_ * 8, &Bl[BUF][NHh][c_ * 8]);\
    }                                                                          \
  } while (0)
#define READ_AQ(BUF, MH)                                                       \
  do {                                                                         \
    _Pragma("unroll")                                                          \
    for (int mi_ = 0; mi_ < 4; ++mi_) {                                        \
      int ix_ = wm * 64 + mi_ * 16 + lr;                                       \
      _Pragma("unroll")                                                        \
      for (int ks_ = 0; ks_ < 2; ++ks_)                                        \
        aq[mi_][ks_] = *(const short8*)&Al[BUF][MH]                            \
            [ix_ * 64 + (((ks_ * 4 + lg) ^ ix_) & 7) * 8];                     \
    }                                                                          \
  } while (0)
#define READ_BN(BUF, NHh, ARR)                                                 \
  do {                                                                         \
    _Pragma("unroll")                                                          \
    for (int ni_ = 0; ni_ < 2; ++ni_) {                                        \
      int ix_ = wn * 32 + ni_ * 16 + lr;                                       \
      _Pragma("unroll")                                                        \
      for (int ks_ = 0; ks_ < 2; ++ks_)                                        \
        ARR[ni_][ks_] = *(const short8*)&Bl[BUF][NHh]                          \
            [ix_ * 64 + (((ks_ * 4 + lg) ^ ix_) & 7) * 8];                     \
    }                                                                          \
  } while (0)
#define MFMA16(MH, NHh, ARR)                                                   \
  do {                                                                         \
    __builtin_amdgcn_s_setprio(1);                                             \
    _Pragma("unroll")                                                          \
    for (int ks_ = 0; ks_ < 2; ++ks_)                                          \
      _Pragma("unroll")                                                        \
      for (int mi_ = 0; mi_ < 4; ++mi_)                                        \
        _Pragma("unroll")                                                      \
        for (int ni_ = 0; ni_ < 2; ++ni_)                                      \
          acc[(MH) * 4 + mi_][(NHh) * 2 + ni_] =                               \
              __builtin_amdgcn_mfma_f32_16x16x32_bf16(                         \
                  aq[mi_][ks_], ARR[ni_][ks_],                                 \
                  acc[(MH) * 4 + mi_][(NHh) * 2 + ni_], 0, 0, 0);              \
    __builtin_amdgcn_s_setprio(0);                                             \
  } while (0)
#define BAR() __builtin_amdgcn_s_barrier()

  const int nt = K >> 6;        // 64 K-tiles (even)
  const int niter = nt >> 1;    // 32 iterations x 2 K-tiles

  // prologue: T0 complete (4 half-tiles) + T1 minus its A-q1 (3 half-tiles)
  STG_AQ(0, 0, 0); STG_BN(0, 0, 0); STG_BN(0, 1, 0); STG_AQ(0, 1, 0);
  STG_AQ(1, 0, 64); STG_BN(1, 0, 64); STG_BN(1, 1, 64);
  asm volatile("s_waitcnt vmcnt(6)" ::: "memory");  // T0's 8 loads landed
  BAR();

  short8 aq[4][2], bn0[2][2], bn1[2][2];
  for (int j = 0; j < niter; ++j) {
    const bool pf = (j + 1 < niter);
    const int k1 = (2 * j + 1) << 6, k2 = (2 * j + 2) << 6, k3 = (2 * j + 3) << 6;

    // ---- ph1: T0 m0n0; stage A(2j+1)-q1 (always in range)
    READ_AQ(0, 0); READ_BN(0, 0, bn0);
    STG_AQ(1, 1, k1);
    BAR(); MFMA16(0, 0, bn0); BAR();

    // ---- ph2: T0 m0n1; stage A(2j+2)-q0
    READ_BN(0, 1, bn1);
    if (pf) STG_AQ(0, 0, k2);
    BAR(); MFMA16(0, 1, bn1); BAR();

    // ---- ph3: T0 m1n0; stage B(2j+2)-n0
    READ_AQ(0, 1);
    if (pf) STG_BN(0, 0, k2);
    BAR(); MFMA16(1, 0, bn0); BAR();

    // ---- ph4: T0 m1n1; stage B(2j+2)-n1; WAIT (T1 ready incl. ph1's A-q1)
    if (pf) STG_BN(0, 1, k2);
    BAR(); MFMA16(1, 1, bn1);
    if (pf) asm volatile("s_waitcnt vmcnt(6)" ::: "memory");
    else    asm volatile("s_waitcnt vmcnt(0)" ::: "memory");
    BAR();

    // ---- ph5: T1 m0n0; stage A(2j+2)-q1
    READ_AQ(1, 0); READ_BN(1, 0, bn0);
    if (pf) STG_AQ(0, 1, k2);
    BAR(); MFMA16(0, 0, bn0); BAR();

    // ---- ph6: T1 m0n1; stage A(2j+3)-q0
    READ_BN(1, 1, bn1);
    if (pf) STG_AQ(1, 0, k3);
    BAR(); MFMA16(0, 1, bn1); BAR();

    // ---- ph7: T1 m1n0; stage B(2j+3)-n0
    READ_AQ(1, 1);
    if (pf) STG_BN(1, 0, k3);
    BAR(); MFMA16(1, 0, bn0); BAR();

    // ---- ph8: T1 m1n1; stage B(2j+3)-n1; WAIT (T0' = tile 2j+2 ready)
    if (pf) STG_BN(1, 1, k3);
    BAR(); MFMA16(1, 1, bn1);
    if (pf) {
      asm volatile("s_waitcnt vmcnt(6)" ::: "memory");
      BAR();
    }
  }
#undef STG_AQ
#undef STG_BN
#undef READ_AQ
#undef READ_BN
#undef MFMA16
#undef BAR

  // ---- epilogue (acc[miG][niG]: m = wm*128 + miG*16, n = wn*64 + niG*16)
#pragma unroll
  for (int mi = 0; mi < 8; ++mi)
#pragma unroll
    for (int ni = 0; ni < 4; ++ni)
#pragma unroll
      for (int v = 0; v < 4; ++v) {
        int m = bm + wm * 128 + mi * 16 + lg * 4 + v;
        int n = bn + wn * 64 + ni * 16 + lr;
        float val = acc[mi][ni][v];
        if (ROPE) {
          int srow = m & (S_ - 1);
          int j = (n & (HD - 1)) >> 1;
          float c = fc[(size_t)srow * 64 + j];
          float s = fs[(size_t)srow * 64 + j];
          float partner = __shfl_xor(val, 1);
          val = (n & 1) ? (val * c + partner * s) : (val * c - partner * s);
          val *= (0.08838834764831845f * 1.44269504088896340f);  // attn scale (log2)
        }
        if (MODE == 0) {
          ((float*)Cout)[(size_t)m * N + n] = val;
        } else if (MODE == 1) {
          int b = m >> 11, s = m & (S_ - 1), hh = n >> 7, d = n & (HD - 1);
          ((u16*)Cout)[(((size_t)(b * Hh + hh)) * S_ + s) * HD + d] = f2bf(val);
        } else {
          int b = m >> 11, s = m & (S_ - 1), hh = n >> 7, d = n & (HD - 1);
          ((u16*)Cout)[(((size_t)(b * Hh + hh)) * HD + d) * S_ + s] = f2bf(val);
        }
      }
}

// ---------------- merged K+V projection (128^2 2-phase), blockIdx.z selects ----
__global__ __launch_bounds__(256)
void gemm_kv(const u16* __restrict__ Xb, const u16* __restrict__ Wk,
             const u16* __restrict__ Wv, u16* __restrict__ Kr, u16* __restrict__ Vt,
             const float* __restrict__ fc, const float* __restrict__ fs) {
  const int tid = threadIdx.x;
  const int lid = tid & 63, w = tid >> 6;
  const int lr = lid & 15, lg = lid >> 4;
  const int wm = w >> 1, wn = w & 1;
  const int zz = blockIdx.z;
  const u16* Bw = zz ? Wv : Wk;
  const int K = D_;

  const int gx = gridDim.x;
  const int nwg = gx * gridDim.y;
  const int lin = blockIdx.y * gx + blockIdx.x;
  const int cpx = nwg >> 3;
  const int lin2 = (lin & 7) * cpx + (lin >> 3);
  const int bm = (lin2 / gx) * 128, bn = (lin2 % gx) * 128;

  __shared__ __align__(16) u16 Al[128 * 64];
  __shared__ __align__(16) u16 Bl[128 * 64];
  f32x4 acc[4][4];
#pragma unroll
  for (int i = 0; i < 4; ++i)
#pragma unroll
    for (int j = 0; j < 4; ++j) acc[i][j] = (f32x4){0.f, 0.f, 0.f, 0.f};

  for (int k0 = 0; k0 < K; k0 += 64) {
    __syncthreads();
#pragma unroll
    for (int i = 0; i < 4; ++i) {
      int c = i * 256 + tid;
      int row = c >> 3, cb = c & 7;
      int cbs = (cb ^ row) & 7;
      load_lds16(Xb + (size_t)(bm + row) * K + k0 + cbs * 8, &Al[c * 8]);
    }
#pragma unroll
    for (int i = 0; i < 4; ++i) {
      int c = i * 256 + tid;
      int row = c >> 3, cb = c & 7;
      int cbs = (cb ^ row) & 7;
      load_lds16(Bw + (size_t)(bn + row) * K + k0 + cbs * 8, &Bl[c * 8]);
    }
    __syncthreads();
#pragma unroll
    for (int ks = 0; ks < 2; ++ks) {
      short8 af[4], bf[4];
#pragma unroll
      for (int mi = 0; mi < 4; ++mi) {
        int row = wm * 64 + mi * 16 + lr;
        af[mi] = *(const short8*)&Al[row * 64 + (((ks * 4 + lg) ^ row) & 7) * 8];
      }
#pragma unroll
      for (int ni = 0; ni < 4; ++ni) {
        int row = wn * 64 + ni * 16 + lr;
        bf[ni] = *(const short8*)&Bl[row * 64 + (((ks * 4 + lg) ^ row) & 7) * 8];
      }
#pragma unroll
      for (int mi = 0; mi < 4; ++mi)
#pragma unroll
        for (int ni = 0; ni < 4; ++ni)
          acc[mi][ni] = __builtin_amdgcn_mfma_f32_16x16x32_bf16(af[mi], bf[ni], acc[mi][ni], 0, 0, 0);
    }
  }
#pragma unroll
  for (int mi = 0; mi < 4; ++mi)
#pragma unroll
    for (int ni = 0; ni < 4; ++ni)
#pragma unroll
      for (int v = 0; v < 4; ++v) {
        int m = bm + wm * 64 + mi * 16 + lg * 4 + v;
        int n = bn + wn * 64 + ni * 16 + lr;
        float val = acc[mi][ni][v];
        int b = m >> 11, s = m & (S_ - 1), hh = n >> 7, d = n & (HD - 1);
        if (zz == 0) {
          int j = d >> 1;
          float c = fc[(size_t)s * 64 + j];
          float sn = fs[(size_t)s * 64 + j];
          float partner = __shfl_xor(val, 1);
          val = (n & 1) ? (val * c + partner * sn) : (val * c - partner * sn);
          Kr[(((size_t)(b * NKV + hh)) * S_ + s) * HD + d] = f2bf(val);
        } else {
          int x = s & 31;
          int sp = (s & ~31) | (((x >> 2) & 3) * 8 + ((x >> 4) & 1) * 4 + (x & 3));
          Vt[(((size_t)(b * NKV + hh)) * HD + d) * S_ + sp] = f2bf(val);
        }
      }
}

// ---------------- Flash attention, swapped-QK + zero-shuffle PV ----------------
__global__ __launch_bounds__(512, 4)
void attn_k(const u16* __restrict__ Qr, const u16* __restrict__ Kr,
            const u16* __restrict__ Vt, u16* __restrict__ Ao) {
  const int xp = blockIdx.x, h = blockIdx.y, b = blockIdx.z;
  const int kvh = h >> 2;
  const int tid = threadIdx.x, lid = tid & 63, w = tid >> 6;
  const int lr = lid & 15, lg = lid >> 4;
  __shared__ __align__(16) u16 Kl[2][64 * 128];
  __shared__ __align__(16) u16 Vl[2][128 * 64];

  const size_t qbase = ((size_t)(b * NH + h)) * S_ * HD;
  const size_t kbase = ((size_t)(b * NKV + kvh)) * S_ * HD;
  const size_t vbase = ((size_t)(b * NKV + kvh)) * HD * S_;

#define STAGE(BUF, KT)                                                              \
  do {                                                                              \
    _Pragma("unroll")                                                               \
    for (int i_ = 0; i_ < 2; ++i_) {                                                \
      int c_ = i_ * 512 + tid;                                                      \
      int row_ = c_ >> 4, cb_ = c_ & 15;                                            \
      int cbs_ = (cb_ & 8) | ((cb_ ^ row_) & 7);                                    \
      load_lds16(&Kr[kbase + (size_t)((KT) + row_) * HD + cbs_ * 8],                \
                 &Kl[BUF][(i_ * 512 + w * 64) * 8]);                                \
    }                                                                               \
    _Pragma("unroll")                                                               \
    for (int i_ = 0; i_ < 2; ++i_) {                                                \
      int c_ = i_ * 512 + tid;                                                      \
      int d_ = c_ >> 3, cb_ = c_ & 7;                                               \
      int cbs_ = (cb_ ^ d_) & 7;                                                    \
      load_lds16(&Vt[vbase + (size_t)d_ * S_ + (KT) + cbs_ * 8],                    \
                 &Vl[BUF][(i_ * 512 + w * 64) * 8]);                                \
    }                                                                               \
  } while (0)

  for (int part = 0; part < 2; ++part) {
    const int qi = part ? xp : (15 - xp);
    const int qb = qi * 128;
    const int ntiles = qi * 2 + 2;
    const int q_abs = qb + w * 16 + lr;

    short8 qf[4];
#pragma unroll
    for (int ks = 0; ks < 4; ++ks)
      qf[ks] = *(const short8*)&Qr[qbase + (size_t)q_abs * HD + ks * 32 + lg * 8];

    float m2 = -3.0e38f, osum = 0.f;
    f32x4 oacc[8];
#pragma unroll
    for (int nd = 0; nd < 8; ++nd) oacc[nd] = (f32x4){0.f, 0.f, 0.f, 0.f};

    STAGE(0, 0);
    __syncthreads();
    int cur = 0;

    for (int t = 0; t < ntiles; ++t) {
      const int kt = t * 64;
      if (t + 1 < ntiles) STAGE(cur ^ 1, kt + 64);

      f32x4 sc[4];
#pragma unroll
      for (int ni = 0; ni < 4; ++ni) sc[ni] = (f32x4){0.f, 0.f, 0.f, 0.f};
      __builtin_amdgcn_s_setprio(1);
#pragma unroll
      for (int ks = 0; ks < 4; ++ks) {
#pragma unroll
        for (int ni = 0; ni < 4; ++ni) {
          int row = ni * 16 + lr;
          int ch = ks * 4 + lg;
          int chs = (ch & 8) | ((ch ^ row) & 7);
          short8 kf = *(const short8*)&Kl[cur][row * 128 + chs * 8];
          sc[ni] = __builtin_amdgcn_mfma_f32_16x16x32_bf16(kf, qf[ks], sc[ni], 0, 0, 0);
        }
      }
      __builtin_amdgcn_s_setprio(0);

      const bool edge = (kt + 64 > qb);
      if (edge) {
#pragma unroll
        for (int ni = 0; ni < 4; ++ni)
#pragma unroll
          for (int v = 0; v < 4; ++v) {
            int kv = kt + ni * 16 + lg * 4 + v;
            if (kv > q_abs) sc[ni][v] = -3.0e38f;
          }
      }
      float mab = fmaxf(fmaxf(fmaxf(sc[0][0], sc[0][1]), fmaxf(sc[0][2], sc[0][3])),
                        fmaxf(fmaxf(sc[1][0], sc[1][1]), fmaxf(sc[1][2], sc[1][3])));
      float mcd = fmaxf(fmaxf(fmaxf(sc[2][0], sc[2][1]), fmaxf(sc[2][2], sc[2][3])),
                        fmaxf(fmaxf(sc[3][0], sc[3][1]), fmaxf(sc[3][2], sc[3][3])));
      float mx = fmaxf(mab, mcd);
      mx = fmaxf(mx, __shfl_xor(mx, 16));
      mx = fmaxf(mx, __shfl_xor(mx, 32));

      if (__any(mx > m2 + 8.0f)) {
        float mnew = fmaxf(m2, mx);
        float fr = exp2f(m2 - mnew);
        m2 = mnew;
        osum *= fr;
#pragma unroll
        for (int nd = 0; nd < 8; ++nd) oacc[nd] *= fr;
      }

      u32x4 pw0, pw1;
      float ps = 0.f;
#pragma unroll
      for (int ni = 0; ni < 4; ++ni) {
#pragma unroll
        for (int p = 0; p < 2; ++p) {
          float e0 = exp2f(sc[ni][2 * p] - m2);
          float e1 = exp2f(sc[ni][2 * p + 1] - m2);
          ps += e0 + e1;
          u32 pk = cvtpk_bf16(e0, e1);
          if (ni < 2) pw0[(ni & 1) * 2 + p] = pk;
          else        pw1[(ni & 1) * 2 + p] = pk;
        }
      }
      osum += ps;
      const short8 pf0 = u32x4_to_short8(pw0);
      const short8 pf1 = u32x4_to_short8(pw1);

      __builtin_amdgcn_s_setprio(1);
#pragma unroll
      for (int ks = 0; ks < 2; ++ks) {
        const short8 pfk = ks ? pf1 : pf0;
#pragma unroll
        for (int nd = 0; nd < 8; ++nd) {
          int rowv = nd * 16 + lr;
          int ch = ks * 4 + lg;
          short8 vf = *(const short8*)&Vl[cur][rowv * 64 + ((ch ^ rowv) & 7) * 8];
          oacc[nd] = __builtin_amdgcn_mfma_f32_16x16x32_bf16(vf, pfk, oacc[nd], 0, 0, 0);
        }
      }
      __builtin_amdgcn_s_setprio(0);
      __syncthreads();
      cur ^= 1;
    }

    float os = osum;
    os += __shfl_xor(os, 16);
    os += __shfl_xor(os, 32);
    const float inv = 1.0f / os;
    const size_t orow = ((size_t)(b * S_ + q_abs)) * D_ + h * HD;
    u32* AoW = (u32*)Ao;
#pragma unroll
    for (int nd = 0; nd < 8; ++nd) {
#pragma unroll
      for (int p = 0; p < 2; ++p) {
        u32 pk = cvtpk_bf16(oacc[nd][2 * p] * inv, oacc[nd][2 * p + 1] * inv);
        AoW[(orow + nd * 16 + lg * 4 + 2 * p) >> 1] = pk;
      }
    }
  }
#undef STAGE
}

// ---------------- host launch ----------------
extern "C" void kernel_launch(void* const* d_in, const int* in_sizes, int n_in,
                              void* d_out, int out_size, void* d_ws, size_t ws_size,
                              hipStream_t stream) {
  const float* x  = (const float*)d_in[0];
  const float* wq = (const float*)d_in[1];
  const float* wk = (const float*)d_in[2];
  const float* wv = (const float*)d_in[3];
  const float* wo = (const float*)d_in[4];
  const float* fc = (const float*)d_in[5];
  const float* fs = (const float*)d_in[6];

  const size_t SZ_X  = (size_t)B_ * S_ * D_ * 2;
  const size_t SZ_WQ = (size_t)D_ * D_ * 2;
  const size_t SZ_WK = (size_t)NKV * HD * D_ * 2;
  char* ws = (char*)d_ws;
  u16* Xb  = (u16*)(ws);
  u16* Wqb = (u16*)(ws + SZ_X);
  u16* Wkb = (u16*)(ws + SZ_X + SZ_WQ);
  u16* Wvb = (u16*)(ws + SZ_X + SZ_WQ + SZ_WK);
  u16* Wob = (u16*)(ws + SZ_X + SZ_WQ + 2 * SZ_WK);
  u16* Qr  = (u16*)(ws + SZ_X + 2 * SZ_WQ + 2 * SZ_WK);
  u16* Kr  = (u16*)(ws + 2 * SZ_X + 2 * SZ_WQ + 2 * SZ_WK);
  u16* Vt  = (u16*)(ws + 2 * SZ_X + 2 * SZ_WQ + 3 * SZ_WK);
  u16* Ao  = (u16*)(ws + 2 * SZ_X + 2 * SZ_WQ + 4 * SZ_WK);
  const size_t NEEDED = 3 * SZ_X + 2 * SZ_WQ + 4 * SZ_WK;
  if (ws_size < NEEDED) return;

  cvt_all<<<28672, 256, 0, stream>>>(x, wq, wk, wv, wo, Xb, Wqb, Wkb, Wvb, Wob);

  gemm256<1, true><<<dim3(16, 16), 512, 0, stream>>>(
      Xb, Wqb, Qr, B_ * S_, D_, D_, NH, fc, fs);
  gemm_kv<<<dim3(8, 32, 2), 256, 0, stream>>>(Xb, Wkb, Wvb, Kr, Vt, fc, fs);

  attn_k<<<dim3(8, NH, B_), 512, 0, stream>>>(Qr, Kr, Vt, Ao);

  gemm256<0, false><<<dim3(16, 16), 512, 0, stream>>>(
      Ao, Wob, d_out, B_ * S_, D_, D_, 0, nullptr, nullptr);
}